// Round 7
// baseline (540.143 us; speedup 1.0000x reference)
//
#include <hip/hip_runtime.h>
#include <math.h>

#define N_NODES 50000
#define E_EDGES 250000
#define HID 64
#define HD 256          // NHEADS * HID
#define L_LAYERS 2
#define IN_DIM_ 256
#define ATT_SCALE 0.125f
#define LOG2E 1.44269504f
#define EPS_BN 1e-5f
#define NCHUNK 49       // ceil(50000/1024)
#define GX 782          // ceil(50000/64)

#define PACK_REL (6 * 512 * 64)
#define PACK_FC  (2 * 64 * 64)
#define PACK_DIM (256 * 64)
#define HIST_B   2930   // ceil(750000/256)
#define PACK_B   864    // (PACK_REL+PACK_FC+PACK_DIM)/256
#define CVT_B    3125   // 3.2M/4/256
#define PROJ_B   (GX * 3)   // py folded into the block (x8 work per block)

#define NBUCK 782       // ceil(50000/64) buckets per relation (64 nodes/bucket)
#define P2_B  (3 * NBUCK)
#define BCSTR 32        // bucket-cursor stride in ints: one 128B line per counter

#define TS 72           // LDS tile row stride in shorts (64 + 8 pad; 144B rows, 16B-aligned)

typedef __attribute__((ext_vector_type(8))) short bf16x8;
typedef __attribute__((ext_vector_type(4))) float f32x4;

static __device__ __forceinline__ unsigned short f2bf(float f) {
    unsigned u = __float_as_uint(f);
    unsigned r = (u + 0x7fff + ((u >> 16) & 1)) >> 16;
    return (unsigned short)r;
}
static __device__ __forceinline__ float bf2f(unsigned u) {
    return __uint_as_float(u << 16);
}

// sum across each 16-lane row via DPP butterfly (4 VALU adds, no LDS)
static __device__ __forceinline__ float rowsum16(float x) {
    int t;
    t = __builtin_amdgcn_update_dpp(0, __float_as_int(x), 0xB1, 0xf, 0xf, true);  // quad_perm(1,0,3,2)
    x += __int_as_float(t);
    t = __builtin_amdgcn_update_dpp(0, __float_as_int(x), 0x4E, 0xf, 0xf, true);  // quad_perm(2,3,0,1)
    x += __int_as_float(t);
    t = __builtin_amdgcn_update_dpp(0, __float_as_int(x), 0x141, 0xf, 0xf, true); // row_half_mirror
    x += __int_as_float(t);
    t = __builtin_amdgcn_update_dpp(0, __float_as_int(x), 0x140, 0xf, 0xf, true); // row_mirror
    x += __int_as_float(t);
    return x;
}

// ----------------------------- scan (3-phase) --------------------------------
// count is XCD-privatized: 8 copies laid out [8][3][N_NODES]; scans sum them.

__global__ __launch_bounds__(256) void scan_partial(const int* __restrict__ count,
                                                    int* __restrict__ bsum) {
    int b = blockIdx.x;                 // 0..146
    int r = b / NCHUNK, ch = b - r * NCHUNK;
    int tid = threadIdx.x;
    int i0 = ch * 1024 + tid * 4;
    int s = 0;
    if (i0 + 3 < N_NODES) {
        #pragma unroll
        for (int c = 0; c < 8; ++c) {
            int4 v = *(const int4*)(count + (size_t)(c * 3 + r) * N_NODES + i0);
            s += v.x + v.y + v.z + v.w;
        }
    } else {
        for (int j = 0; j < 4; ++j)
            if (i0 + j < N_NODES)
                for (int c = 0; c < 8; ++c)
                    s += count[(size_t)(c * 3 + r) * N_NODES + i0 + j];
    }
    for (int o = 1; o < 64; o <<= 1) s += __shfl_xor(s, o, 64);
    __shared__ int wsum[4];
    if ((tid & 63) == 0) wsum[tid >> 6] = s;
    __syncthreads();
    if (tid == 0) bsum[b] = wsum[0] + wsum[1] + wsum[2] + wsum[3];
}

__global__ __launch_bounds__(256) void scan_mid(const int* __restrict__ bsum,
                                                int* __restrict__ bpre) {
    __shared__ int A[256], B[256];
    int tid = threadIdx.x;
    int v = (tid < 3 * NCHUNK) ? bsum[tid] : 0;
    int segStart = (tid / NCHUNK) * NCHUNK;
    A[tid] = v;
    __syncthreads();
    int* s = A; int* d = B;
    for (int o = 1; o < 256; o <<= 1) {
        int x = s[tid];
        if (tid - o >= segStart) x += s[tid - o];
        d[tid] = x;
        __syncthreads();
        int* t = s; s = d; d = t;
    }
    if (tid < 3 * NCHUNK) bpre[tid] = s[tid] - v;
}

__global__ __launch_bounds__(256) void scan_final(const int* __restrict__ count,
                                                  const int* __restrict__ bpre,
                                                  int* __restrict__ row_off,
                                                  int* __restrict__ cursor,
                                                  int* __restrict__ bcur) {
    int b = blockIdx.x;
    int r = b / NCHUNK, ch = b - r * NCHUNK;
    int tid = threadIdx.x;
    int i0 = ch * 1024 + tid * 4;
    int v[4] = {0, 0, 0, 0};
    if (i0 + 3 < N_NODES) {
        #pragma unroll
        for (int c = 0; c < 8; ++c) {
            int4 t = *(const int4*)(count + (size_t)(c * 3 + r) * N_NODES + i0);
            v[0] += t.x; v[1] += t.y; v[2] += t.z; v[3] += t.w;
        }
    } else {
        for (int j = 0; j < 4; ++j)
            if (i0 + j < N_NODES)
                for (int c = 0; c < 8; ++c)
                    v[j] += count[(size_t)(c * 3 + r) * N_NODES + i0 + j];
    }
    int tsum = v[0] + v[1] + v[2] + v[3];
    __shared__ int A[256], B[256];
    A[tid] = tsum;
    __syncthreads();
    int* s = A; int* d = B;
    for (int o = 1; o < 256; o <<= 1) {
        int x = s[tid];
        if (tid >= o) x += s[tid - o];
        d[tid] = x;
        __syncthreads();
        int* t = s; s = d; d = t;
    }
    int run = bpre[b] + s[tid] - tsum;
    int* ro = row_off + r * (N_NODES + 1);
    int* cu = cursor + r * N_NODES;
    for (int j = 0; j < 4; ++j) {
        int idx = i0 + j;
        if (idx < N_NODES) {
            ro[idx] = run; cu[idx] = run;
            if ((idx & 63) == 0) bcur[(size_t)(r * NBUCK + (idx >> 6)) * BCSTR] = run;
            run += v[j];
        }
    }
    if (ch == NCHUNK - 1 && tid == 255) ro[N_NODES] = E_EDGES;
}

// ----------------------- U1: hist ∪ pack ∪ cvt -------------------------------
// hist: XCD-private copy selected by blockIdx&7 (round-robin block->XCD) so
// the atomic lines stay in one XCD's L2 instead of ping-ponging.

__global__ __launch_bounds__(256) void u1_kernel(
        const int* __restrict__ d0, const int* __restrict__ d1, const int* __restrict__ d2,
        int* __restrict__ count,
        const float* __restrict__ Wsrc, const float* __restrict__ Wdst,
        const float* __restrict__ Wfc, const float* __restrict__ Wdim,
        unsigned short* __restrict__ WtRel, unsigned short* __restrict__ WtFc,
        unsigned short* __restrict__ WtDim,
        const float* __restrict__ x, unsigned short* __restrict__ xb) {
    int b = blockIdx.x;
    if (b < HIST_B) {
        int i = b * 256 + threadIdx.x;
        if (i < 3 * E_EDGES) {
            int r = i / E_EDGES;
            int e = i - r * E_EDGES;
            const int* dst = (r == 0) ? d0 : ((r == 1) ? d1 : d2);
            int c = b & 7;
            atomicAdd(&count[(size_t)(c * 3 + r) * N_NODES + dst[e]], 1);
        }
    } else if (b < HIST_B + PACK_B) {
        int i = (b - HIST_B) * 256 + threadIdx.x;
        if (i < PACK_REL) {
            int k = i & 63;
            int n = (i >> 6) & 511;
            int lr = i >> 15;
            const float* srcm = (n < 256) ? Wsrc : Wdst;
            WtRel[i] = f2bf(srcm[((size_t)lr * 64 + k) * 256 + (n & 255)]);
        } else if (i < PACK_REL + PACK_FC) {
            int j = i - PACK_REL;
            int l = j >> 12, rem = j & 4095;
            int k = rem & 63, n = rem >> 6;
            WtFc[j] = f2bf(Wfc[(size_t)l * 4096 + k * 64 + n]);
        } else if (i < PACK_REL + PACK_FC + PACK_DIM) {
            int j = i - PACK_REL - PACK_FC;
            int k = j & 63, n = j >> 6;
            WtDim[j] = f2bf(Wdim[(size_t)k * 256 + n]);
        }
    } else {
        int i = ((b - HIST_B - PACK_B) * 256 + threadIdx.x) * 4;
        if (i < N_NODES * HID) {
            float4 v = *(const float4*)(x + i);
            uint2 o;
            o.x = (unsigned)f2bf(v.x) | ((unsigned)f2bf(v.y) << 16);
            o.y = (unsigned)f2bf(v.z) | ((unsigned)f2bf(v.w) << 16);
            *(uint2*)(xb + i) = o;
        }
    }
}

// -------------------- pass 1: bucket-append (dst16|src16) --------------------
// Appends to per-relation bucket streams at moving frontiers. Each frontier
// counter owns a full 128B line (BCSTR pad): atomics to different buckets
// never share a line (the round-2 200us same-line-serialization bug).

__global__ __launch_bounds__(256) void eb_kernel(
        const int* __restrict__ s0, const int* __restrict__ d0,
        const int* __restrict__ s1, const int* __restrict__ d1,
        const int* __restrict__ s2, const int* __restrict__ d2,
        int* __restrict__ bcur, unsigned* __restrict__ ebuf) {
    int i = blockIdx.x * 256 + threadIdx.x;
    if (i >= 3 * E_EDGES) return;
    int r = i / E_EDGES;
    int e = i - r * E_EDGES;
    const int* src = (r == 0) ? s0 : ((r == 1) ? s1 : s2);
    const int* dst = (r == 0) ? d0 : ((r == 1) ? d1 : d2);
    int d = dst[e], s = src[e];
    int pos = atomicAdd(&bcur[(size_t)(r * NBUCK + (d >> 6)) * BCSTR], 1);
    ebuf[(size_t)r * E_EDGES + pos] = (unsigned)d | ((unsigned)s << 16);
}

// --------------------------- MFMA projection body ----------------------------
// One block per (node-block px, relation). B-fragments (hB rows, node side)
// are loaded ONCE into registers and reused across all 8 feature blocks.
// Per py: 8 MFMA -> padded LDS tile -> full-128B-line sweep to out.

static __device__ __forceinline__ void proj_body8(int bx,
        const unsigned short* __restrict__ hB, const unsigned short* __restrict__ Wt,
        unsigned short* __restrict__ out, int M, unsigned short* tile) {
    int tid = threadIdx.x;
    int wave = tid >> 6, lane = tid & 63;
    int q = lane >> 4, li = lane & 15;
    int nodeLoc = (wave >> 1) * 32;
    int featLoc = (wave & 1) * 32;
    int nodeBase = bx * 64 + nodeLoc;

    // B-fragments: loaded once, reused for all 8 py iterations
    bf16x8 bfr[2][2];
    #pragma unroll
    for (int t = 0; t < 2; ++t) {
        int node = nodeBase + t * 16 + li; if (node >= M) node = M - 1;
        const unsigned short* bp = hB + (size_t)node * 64 + q * 8;
        #pragma unroll
        for (int s = 0; s < 2; ++s) bfr[t][s] = *(const bf16x8*)(bp + s * 32);
    }

    #pragma unroll
    for (int py = 0; py < 8; ++py) {
        int featBase = py * 64 + featLoc;
        bf16x8 afr[2][2];
        #pragma unroll
        for (int t = 0; t < 2; ++t) {
            const unsigned short* ap = Wt + (size_t)(featBase + t * 16 + li) * 64 + q * 8;
            #pragma unroll
            for (int s = 0; s < 2; ++s) afr[t][s] = *(const bf16x8*)(ap + s * 32);
        }
        f32x4 acc[2][2];
        #pragma unroll
        for (int a = 0; a < 2; ++a)
            #pragma unroll
            for (int bq = 0; bq < 2; ++bq)
                #pragma unroll
                for (int i = 0; i < 4; ++i) acc[a][bq][i] = 0.f;
        #pragma unroll
        for (int s = 0; s < 2; ++s)
            #pragma unroll
            for (int ft = 0; ft < 2; ++ft)
                #pragma unroll
                for (int nt = 0; nt < 2; ++nt)
                    acc[ft][nt] = __builtin_amdgcn_mfma_f32_16x16x32_bf16(afr[ft][s], bfr[nt][s], acc[ft][nt], 0, 0, 0);

        // stage this 64x64 tile to LDS (local coords)
        #pragma unroll
        for (int ft = 0; ft < 2; ++ft) {
            int fl = featLoc + ft * 16 + q * 4;
            #pragma unroll
            for (int nt = 0; nt < 2; ++nt) {
                int nl = nodeLoc + nt * 16 + li;
                unsigned lo = (unsigned)f2bf(acc[ft][nt][0]) | ((unsigned)f2bf(acc[ft][nt][1]) << 16);
                unsigned hi = (unsigned)f2bf(acc[ft][nt][2]) | ((unsigned)f2bf(acc[ft][nt][3]) << 16);
                uint2 pk; pk.x = lo; pk.y = hi;
                *(uint2*)(tile + nl * TS + fl) = pk;
            }
        }
        __syncthreads();
        // coalesced sweep: 8 lanes cover one node's 128B chunk, full-line stores
        #pragma unroll
        for (int p = 0; p < 2; ++p) {
            int idx = p * 256 + tid;          // 0..511
            int nl = idx >> 3, sg = idx & 7;
            int node = bx * 64 + nl;
            if (node < M) {
                uint4 v = *(const uint4*)(tile + nl * TS + sg * 8);
                *(uint4*)(out + (size_t)node * 512 + py * 64 + sg * 8) = v;
            }
        }
        __syncthreads();    // tile reused next py
    }
}

// ------------- U2b: CSR pass 2 (bucket-local) ∪ proj(layer 0) ----------------
// pass2: one block per bucket; cursor atomics + csr writes confined to a
// line-aligned block-owned window. Additionally fills itab[rel][dst][8]: the
// first 8 src indices of each row, dst-indexed, so agg_fused can load them
// WITHOUT first resolving row_off (removes one level of the dependent chain).

__global__ __launch_bounds__(256) void u2b_kernel(
        const int* __restrict__ row_off, int* __restrict__ cursor,
        const unsigned* __restrict__ ebuf, int* __restrict__ csr_src,
        int* __restrict__ itab,
        const unsigned short* __restrict__ xb, const unsigned short* __restrict__ WtRel0,
        unsigned short* __restrict__ p0, unsigned short* __restrict__ p1,
        unsigned short* __restrict__ p2) {
    __shared__ __align__(16) unsigned short tile[64 * TS];
    int b = blockIdx.x;
    if (b < P2_B) {
        int r = b / NBUCK, bk = b - r * NBUCK;
        int n0 = bk << 6;
        int n1 = n0 + 64; if (n1 > N_NODES) n1 = N_NODES;
        const int* ro = row_off + r * (N_NODES + 1);
        int* ro_s = (int*)tile;     // pass2 doesn't use the MFMA tile
        if (threadIdx.x < 64 && n0 + (int)threadIdx.x < N_NODES)
            ro_s[threadIdx.x] = ro[n0 + threadIdx.x];
        __syncthreads();
        int lo = ro[n0], hi = ro[n1];
        int* cu = cursor + r * N_NODES;
        int* cs = csr_src + r * E_EDGES;
        int* it = itab + (size_t)r * N_NODES * 8;
        const unsigned* eb = ebuf + (size_t)r * E_EDGES;
        for (int t = lo + threadIdx.x; t < hi; t += 256) {
            unsigned v = eb[t];
            int d = v & 0xffff;
            int s = (int)(v >> 16);
            int pos = atomicAdd(&cu[d], 1);
            cs[pos] = s;
            int slot = pos - ro_s[d - n0];
            if (slot < 8) it[(size_t)d * 8 + slot] = s;
        }
    } else {
        int b2 = b - P2_B;
        int px = b2 % GX;
        int pz = b2 / GX;
        unsigned short* out = (pz == 0) ? p0 : ((pz == 1) ? p1 : p2);
        proj_body8(px, xb, WtRel0 + (size_t)pz * 512 * 64, out, N_NODES, tile);
    }
}

// proj for layer 1 (no CSR work to overlap)
__global__ __launch_bounds__(256) void gemm_proj3(const unsigned short* __restrict__ hB,
                                                  const unsigned short* __restrict__ WtL,
                                                  unsigned short* __restrict__ p0,
                                                  unsigned short* __restrict__ p1,
                                                  unsigned short* __restrict__ p2,
                                                  int M) {
    __shared__ __align__(16) unsigned short tile[64 * TS];
    int r = blockIdx.z;
    unsigned short* out = (r == 0) ? p0 : ((r == 1) ? p1 : p2);
    proj_body8(blockIdx.x, hB, WtL + (size_t)r * 512 * 64, out, M, tile);
}

__global__ __launch_bounds__(256) void gemm_f32out(const unsigned short* __restrict__ hB,
                                                   const unsigned short* __restrict__ Wt,
                                                   const float* __restrict__ bias,
                                                   float* __restrict__ out,
                                                   int M, int Nout, int relu) {
    int tid = threadIdx.x;
    int wave = tid >> 6, lane = tid & 63;
    int q = lane >> 4, li = lane & 15;
    int nodeBase = blockIdx.x * 64 + (wave >> 1) * 32;
    int featBase = blockIdx.y * 64 + (wave & 1) * 32;

    const unsigned short* aptr[2];
    const unsigned short* bptr[2];
    #pragma unroll
    for (int t = 0; t < 2; ++t) {
        aptr[t] = Wt + (size_t)(featBase + t * 16 + li) * 64 + q * 8;
        int node = nodeBase + t * 16 + li; if (node >= M) node = M - 1;
        bptr[t] = hB + (size_t)node * 64 + q * 8;
    }
    f32x4 acc[2][2];
    #pragma unroll
    for (int a = 0; a < 2; ++a)
        #pragma unroll
        for (int bq = 0; bq < 2; ++bq)
            #pragma unroll
            for (int i = 0; i < 4; ++i) acc[a][bq][i] = 0.f;

    #pragma unroll
    for (int s = 0; s < 2; ++s) {
        bf16x8 a[2], b[2];
        #pragma unroll
        for (int t = 0; t < 2; ++t) {
            a[t] = *(const bf16x8*)(aptr[t] + s * 32);
            b[t] = *(const bf16x8*)(bptr[t] + s * 32);
        }
        #pragma unroll
        for (int ft = 0; ft < 2; ++ft)
            #pragma unroll
            for (int nt = 0; nt < 2; ++nt)
                acc[ft][nt] = __builtin_amdgcn_mfma_f32_16x16x32_bf16(a[ft], b[nt], acc[ft][nt], 0, 0, 0);
    }
    #pragma unroll
    for (int ft = 0; ft < 2; ++ft) {
        int f0 = featBase + ft * 16 + q * 4;
        float b0 = bias[f0], b1 = bias[f0 + 1], b2 = bias[f0 + 2], b3 = bias[f0 + 3];
        #pragma unroll
        for (int nt = 0; nt < 2; ++nt) {
            int node = nodeBase + nt * 16 + li;
            if (node >= M) continue;
            float4 o;
            o.x = acc[ft][nt][0] + b0; o.y = acc[ft][nt][1] + b1;
            o.z = acc[ft][nt][2] + b2; o.w = acc[ft][nt][3] + b3;
            if (relu) {
                o.x = fmaxf(o.x, 0.f); o.y = fmaxf(o.y, 0.f);
                o.z = fmaxf(o.z, 0.f); o.w = fmaxf(o.w, 0.f);
            }
            *(float4*)(out + (size_t)node * Nout + f0) = o;
        }
    }
}

// ----------------- fused attention: 3 relations + head-mean ------------------
// One wave per dst node. proj row: [fs(256) | fd(256)] bf16. Softmax without
// max-shift (|logit| clamped); fd pre-scaled by SCALE*log2e.
// Dependent chain is 2 levels for deg<=8 rows (~93%): {row_off, fd, itab}
// all dst-indexed and issued in one burst -> gathers (addresses from itab)
// -> process. Heavy rows use a chunked serial tail via csr_src.

#define AGG_ISSUE8(R, sv, j0, cnt, proj) do {                                   \
    _Pragma("unroll")                                                           \
    for (int t_ = 0; t_ < 8; ++t_) {                                            \
        if (t_ < (cnt)) {                                                       \
            int idx_ = __shfl((sv), (j0) + t_, 64);                             \
            (R)[t_] = *(const uint2*)((proj) + (size_t)idx_ * 512 + lane * 4);  \
        }                                                                       \
    }                                                                           \
} while (0)

#define AGG_PROC8(R, cnt) do {                                                  \
    _Pragma("unroll")                                                           \
    for (int t_ = 0; t_ < 8; ++t_) {                                            \
        if (t_ < (cnt)) {                                                       \
            float s0_ = __uint_as_float((R)[t_].x << 16);                       \
            float s1_ = __uint_as_float((R)[t_].x & 0xffff0000u);               \
            float s2_ = __uint_as_float((R)[t_].y << 16);                       \
            float s3_ = __uint_as_float((R)[t_].y & 0xffff0000u);               \
            float p_ = s0_ * fd0_ + s1_ * fd1_ + s2_ * fd2_ + s3_ * fd3_;       \
            p_ = rowsum16(p_);                                                  \
            p_ = fminf(fmaxf(p_, -60.f), 60.f);                                 \
            float pe_ = __builtin_amdgcn_exp2f(p_);                             \
            den_ += pe_;                                                        \
            a0_ += pe_ * s0_; a1_ += pe_ * s1_;                                 \
            a2_ += pe_ * s2_; a3_ += pe_ * s3_;                                 \
        }                                                                       \
    }                                                                           \
} while (0)

// process one relation: consume prefetched rv[0..cB), then chunked serial
// tail from csr_src (loads its own 64-index chunks; rare, deg>8 only).
#define AGG_REL(proj, fdr, deg, cs, rv, cB) do {                                \
    if ((deg) > 0) {                                                            \
        float fd0_ = bf2f((fdr).x & 0xffff) * FS;                               \
        float fd1_ = __uint_as_float((fdr).x & 0xffff0000u) * FS;               \
        float fd2_ = bf2f((fdr).y & 0xffff) * FS;                               \
        float fd3_ = __uint_as_float((fdr).y & 0xffff0000u) * FS;               \
        float den_ = 0.f, a0_ = 0.f, a1_ = 0.f, a2_ = 0.f, a3_ = 0.f;           \
        AGG_PROC8(rv, cB);                                                      \
        int e_ = (cB);                                                          \
        int sv_ = 0;                                                            \
        int cbase_ = -1;                                                        \
        while (e_ < (deg)) {                                                    \
            int cb_ = e_ & ~63;                                                 \
            if (cb_ != cbase_) {                                                \
                cbase_ = cb_;                                                   \
                int o_ = cb_ + lane;                                            \
                sv_ = (o_ < (deg)) ? (cs)[o_] : 0;                              \
            }                                                                   \
            int j0_ = e_ - cb_;                                                 \
            int nt_ = (deg) - e_; if (nt_ > 8) nt_ = 8;                         \
            if (nt_ > 64 - j0_) nt_ = 64 - j0_;                                 \
            uint2 rt_[8];                                                       \
            AGG_ISSUE8(rt_, sv_, j0_, nt_, proj);                               \
            AGG_PROC8(rt_, nt_);                                                \
            e_ += nt_;                                                          \
        }                                                                       \
        float inv_ = 1.0f / fmaxf(den_, 1e-9f);                                 \
        t0 += a0_ * inv_; t1 += a1_ * inv_;                                     \
        t2 += a2_ * inv_; t3 += a3_ * inv_;                                     \
    }                                                                           \
} while (0)

__global__ __launch_bounds__(256) void agg_fused(const int* __restrict__ row_off,
                                                 const int* __restrict__ csr_src,
                                                 const int* __restrict__ itab,
                                                 const unsigned short* __restrict__ p0,
                                                 const unsigned short* __restrict__ p1,
                                                 const unsigned short* __restrict__ p2,
                                                 unsigned short* __restrict__ hm) {
    int wave = (blockIdx.x * 256 + threadIdx.x) >> 6;
    int lane = threadIdx.x & 63;
    if (wave >= N_NODES) return;
    int dst = wave;
    const float FS = ATT_SCALE * LOG2E;

    // --- phase 0: one parallel burst of dst-indexed loads ---
    // itab (first-8 indices; lanes 0-7 hold slots 0-7, replicated)
    int sv0 = itab[(size_t)dst * 8 + (lane & 7)];
    int sv1 = itab[((size_t)N_NODES + dst) * 8 + (lane & 7)];
    int sv2 = itab[((size_t)2 * N_NODES + dst) * 8 + (lane & 7)];
    // row_off pairs
    const int* ro0 = row_off;
    const int* ro1 = row_off + (N_NODES + 1);
    const int* ro2 = row_off + 2 * (N_NODES + 1);
    int b0 = ro0[dst], e0 = ro0[dst + 1];
    int b1 = ro1[dst], e1 = ro1[dst + 1];
    int b2 = ro2[dst], e2 = ro2[dst + 1];
    // fd rows
    uint2 fdr0 = *(const uint2*)(p0 + (size_t)dst * 512 + 256 + lane * 4);
    uint2 fdr1 = *(const uint2*)(p1 + (size_t)dst * 512 + 256 + lane * 4);
    uint2 fdr2 = *(const uint2*)(p2 + (size_t)dst * 512 + 256 + lane * 4);
    int deg0 = e0 - b0, deg1 = e1 - b1, deg2 = e2 - b2;

    // --- phase 1: first up-to-8 row gathers per rel (addresses from itab) ---
    uint2 rv0[8], rv1[8], rv2[8];
    int c0 = deg0 < 8 ? deg0 : 8;
    int c1 = deg1 < 8 ? deg1 : 8;
    int c2 = deg2 < 8 ? deg2 : 8;
    AGG_ISSUE8(rv0, sv0, 0, c0, p0);
    AGG_ISSUE8(rv1, sv1, 0, c1, p1);
    AGG_ISSUE8(rv2, sv2, 0, c2, p2);

    // --- phase 2: process rel-by-rel ---
    const int* cs0 = csr_src + b0;
    const int* cs1 = csr_src + E_EDGES + b1;
    const int* cs2 = csr_src + 2 * E_EDGES + b2;
    float t0 = 0.f, t1 = 0.f, t2 = 0.f, t3 = 0.f;
    AGG_REL(p0, fdr0, deg0, cs0, rv0, c0);
    AGG_REL(p1, fdr1, deg1, cs1, rv1, c1);
    AGG_REL(p2, fdr2, deg2, cs2, rv2, c2);

    // mean over heads: feature f of head h lives at lane h*16 + f/4, slot f&3
    t0 += __shfl_xor(t0, 16, 64); t0 += __shfl_xor(t0, 32, 64);
    t1 += __shfl_xor(t1, 16, 64); t1 += __shfl_xor(t1, 32, 64);
    t2 += __shfl_xor(t2, 16, 64); t2 += __shfl_xor(t2, 32, 64);
    t3 += __shfl_xor(t3, 16, 64); t3 += __shfl_xor(t3, 32, 64);
    if (lane < 16) {
        unsigned lo = (unsigned)f2bf(t0 * 0.25f) | ((unsigned)f2bf(t1 * 0.25f) << 16);
        unsigned hi = (unsigned)f2bf(t2 * 0.25f) | ((unsigned)f2bf(t3 * 0.25f) << 16);
        uint2 pk; pk.x = lo; pk.y = hi;
        *(uint2*)(hm + (size_t)dst * 64 + lane * 4) = pk;
    }
}

// ----------------------------- batchnorm -------------------------------------

__global__ __launch_bounds__(256) void bn_reduce_kernel(const float* __restrict__ y,
                                                        float* __restrict__ acc1,
                                                        float* __restrict__ acc2) {
    int tid = threadIdx.x;
    int c = tid & 63;
    int g = tid >> 6;
    int rowStart = blockIdx.x * 4 + g;
    int stride = gridDim.x * 4;
    float s1 = 0.f, s2 = 0.f;
    for (int r = rowStart; r < N_NODES; r += stride) {
        float v = y[(size_t)r * 64 + c];
        s1 += v; s2 += v * v;
    }
    __shared__ float l1[4][64], l2[4][64];
    l1[g][c] = s1; l2[g][c] = s2;
    __syncthreads();
    if (g == 0) {
        s1 = l1[0][c] + l1[1][c] + l1[2][c] + l1[3][c];
        s2 = l2[0][c] + l2[1][c] + l2[2][c] + l2[3][c];
        atomicAdd(&acc1[c], s1);
        atomicAdd(&acc2[c], s2);
    }
}

__global__ void bn_apply_kernel(const float* __restrict__ y, const float* __restrict__ acc1,
                                const float* __restrict__ acc2, const float* __restrict__ gamma,
                                const float* __restrict__ beta,
                                unsigned short* __restrict__ outb) {
    int i = blockIdx.x * blockDim.x + threadIdx.x;
    if (i >= N_NODES * HID) return;
    int c = i & 63;
    const float invN = 1.0f / (float)N_NODES;
    float mu = acc1[c] * invN;
    float var = acc2[c] * invN - mu * mu;
    float v = gamma[c] * (y[i] - mu) * rsqrtf(var + EPS_BN) + beta[c];
    outb[i] = f2bf(v);
}

// ----------------------------- launch ----------------------------------------

extern "C" void kernel_launch(void* const* d_in, const int* in_sizes, int n_in,
                              void* d_out, int out_size, void* d_ws, size_t ws_size,
                              hipStream_t stream) {
    const float* x     = (const float*)d_in[0];
    const int* srcs[3] = {(const int*)d_in[1], (const int*)d_in[3], (const int*)d_in[5]};
    const int* dsts[3] = {(const int*)d_in[2], (const int*)d_in[4], (const int*)d_in[6]};
    const float* Wsrc  = (const float*)d_in[7];
    const float* Wdst  = (const float*)d_in[8];
    const float* Wfc   = (const float*)d_in[9];
    const float* bfc   = (const float*)d_in[10];
    const float* gamma = (const float*)d_in[11];
    const float* beta  = (const float*)d_in[12];
    const float* Wdim  = (const float*)d_in[13];
    const float* bdim  = (const float*)d_in[14];
    float* out = (float*)d_out;

    char* ws = (char*)d_ws;
    size_t off = 0;
    auto alloc = [&](size_t bytes) -> void* {
        void* p = ws + off;
        off += (bytes + 255) & ~(size_t)255;
        return p;
    };
    // bnacc + count8 contiguous so one memset zeros both
    float* bnacc  = (float*)alloc(256 * 4);                    // [0..127] l0, [128..255] l1
    int* count    = (int*)alloc((size_t)8 * 3 * N_NODES * 4);  // XCD-private x8
    int* cursor   = (int*)alloc((size_t)3 * N_NODES * 4);
    int* row_off  = (int*)alloc((size_t)3 * (N_NODES + 1) * 4);
    int* csr_src  = (int*)alloc((size_t)3 * E_EDGES * 4);
    int* itab     = (int*)alloc((size_t)3 * N_NODES * 8 * 4);  // first-8 src per (rel,dst)
    int* bcur     = (int*)alloc((size_t)3 * NBUCK * BCSTR * 4); // 1 line per counter
    unsigned* ebuf = (unsigned*)alloc((size_t)3 * E_EDGES * 4);
    int* bsum     = (int*)alloc(256 * 4);
    int* bpre     = (int*)alloc(256 * 4);
    unsigned short* proj0 = (unsigned short*)alloc((size_t)N_NODES * 512 * 2);
    unsigned short* proj1 = (unsigned short*)alloc((size_t)N_NODES * 512 * 2);
    unsigned short* proj2 = (unsigned short*)alloc((size_t)N_NODES * 512 * 2);
    unsigned short* hm    = (unsigned short*)alloc((size_t)N_NODES * HID * 2);
    float* ybuf           = (float*)alloc((size_t)N_NODES * HID * 4);
    unsigned short* xb    = (unsigned short*)alloc((size_t)N_NODES * HID * 2);
    unsigned short* hb0   = (unsigned short*)alloc((size_t)N_NODES * HID * 2);
    unsigned short* hb1   = (unsigned short*)alloc((size_t)N_NODES * HID * 2);
    unsigned short* WtRel = (unsigned short*)alloc((size_t)PACK_REL * 2);
    unsigned short* WtFc  = (unsigned short*)alloc((size_t)PACK_FC * 2);
    unsigned short* WtDim = (unsigned short*)alloc((size_t)PACK_DIM * 2);

    // one memset covers bnacc (1 KB) + count8 (4.8 MB), contiguous
    hipMemsetAsync(bnacc, 0, 1024 + (size_t)8 * 3 * N_NODES * 4, stream);

    // U1: hist ∪ weight-pack ∪ x->bf16 cast
    u1_kernel<<<HIST_B + PACK_B + CVT_B, 256, 0, stream>>>(
        dsts[0], dsts[1], dsts[2], count, Wsrc, Wdst, Wfc, Wdim,
        WtRel, WtFc, WtDim, x, xb);

    scan_partial<<<3 * NCHUNK, 256, 0, stream>>>(count, bsum);
    scan_mid<<<1, 256, 0, stream>>>(bsum, bpre);
    scan_final<<<3 * NCHUNK, 256, 0, stream>>>(count, bpre, row_off, cursor, bcur);

    // CSR pass 1: bucket-append packed (dst,src)
    eb_kernel<<<HIST_B, 256, 0, stream>>>(
        srcs[0], dsts[0], srcs[1], dsts[1], srcs[2], dsts[2], bcur, ebuf);

    // U2b: CSR pass 2 (bucket-local scatter + itab fill) ∪ proj(layer 0)
    u2b_kernel<<<P2_B + PROJ_B, 256, 0, stream>>>(
        row_off, cursor, ebuf, csr_src, itab, xb, WtRel, proj0, proj1, proj2);

    unsigned short* hbufs[2] = {hb0, hb1};
    const unsigned short* hcur = xb;
    for (int l = 0; l < L_LAYERS; ++l) {
        if (l > 0) {
            dim3 g(GX, 1, 3);
            gemm_proj3<<<g, 256, 0, stream>>>(hcur, WtRel + (size_t)l * 3 * 512 * 64,
                                              proj0, proj1, proj2, N_NODES);
        }
        agg_fused<<<(N_NODES + 3) / 4, 256, 0, stream>>>(row_off, csr_src, itab,
                                                         proj0, proj1, proj2, hm);
        dim3 g2(GX, 1);
        gemm_f32out<<<g2, 256, 0, stream>>>(hm, WtFc + (size_t)l * 64 * 64, bfc + (size_t)l * HID,
                                            ybuf, N_NODES, 64, 1);
        float* ba = bnacc + l * 128;
        bn_reduce_kernel<<<256, 256, 0, stream>>>(ybuf, ba, ba + 64);
        bn_apply_kernel<<<(N_NODES * HID + 255) / 256, 256, 0, stream>>>(
            ybuf, ba, ba + 64, gamma + (size_t)l * HID, beta + (size_t)l * HID, hbufs[l]);
        hcur = hbufs[l];
    }
    dim3 g3(GX, IN_DIM_ / 64);
    gemm_f32out<<<g3, 256, 0, stream>>>(hcur, WtDim, bdim, out, N_NODES, IN_DIM_, 0);
}

// Round 8
// 483.241 us; speedup vs baseline: 1.1178x; 1.1178x over previous
//
#include <hip/hip_runtime.h>
#include <math.h>

#define N_NODES 50000
#define E_EDGES 250000
#define HID 64
#define HD 256          // NHEADS * HID
#define L_LAYERS 2
#define IN_DIM_ 256
#define ATT_SCALE 0.125f
#define LOG2E 1.44269504f
#define EPS_BN 1e-5f
#define GX 782          // ceil(50000/64)

#define PACK_REL (6 * 512 * 64)
#define PACK_FC  (2 * 64 * 64)
#define PACK_DIM (256 * 64)
#define HIST_B   2930   // ceil(750000/256)
#define PACK_B   864    // (PACK_REL+PACK_FC+PACK_DIM)/256
#define CVT_B    3125   // 3.2M/4/256
#define PROJ_B   (GX * 3)   // py folded into the block (x8 work per block)

#define NBUCK 782       // ceil(50000/64) buckets per relation (64 nodes/bucket)
#define P2_B  (3 * NBUCK)
#define BCSTR 32        // bucket-cursor stride in ints: one 128B line per counter
#define BCAP  512       // fixed bucket capacity (avg load 320 = Poisson; 512 = +10 sigma)

#define TS 72           // LDS tile row stride in shorts (64 + 8 pad; 144B rows, 16B-aligned)

typedef __attribute__((ext_vector_type(8))) short bf16x8;
typedef __attribute__((ext_vector_type(4))) float f32x4;

static __device__ __forceinline__ unsigned short f2bf(float f) {
    unsigned u = __float_as_uint(f);
    unsigned r = (u + 0x7fff + ((u >> 16) & 1)) >> 16;
    return (unsigned short)r;
}
static __device__ __forceinline__ float bf2f(unsigned u) {
    return __uint_as_float(u << 16);
}

// sum across each 16-lane row via DPP butterfly (4 VALU adds, no LDS)
static __device__ __forceinline__ float rowsum16(float x) {
    int t;
    t = __builtin_amdgcn_update_dpp(0, __float_as_int(x), 0xB1, 0xf, 0xf, true);  // quad_perm(1,0,3,2)
    x += __int_as_float(t);
    t = __builtin_amdgcn_update_dpp(0, __float_as_int(x), 0x4E, 0xf, 0xf, true);  // quad_perm(2,3,0,1)
    x += __int_as_float(t);
    t = __builtin_amdgcn_update_dpp(0, __float_as_int(x), 0x141, 0xf, 0xf, true); // row_half_mirror
    x += __int_as_float(t);
    t = __builtin_amdgcn_update_dpp(0, __float_as_int(x), 0x140, 0xf, 0xf, true); // row_mirror
    x += __int_as_float(t);
    return x;
}

// ------------- U1: bucket-append ∪ weight-pack ∪ x->bf16 cast ----------------
// The bucket-append stream IS the CSR build input: no per-node histogram, no
// 3-phase scan, no separate eb pass. Each frontier counter owns a 128B line
// (BCSTR) so bucket atomics never share a line. Fixed capacity BCAP/bucket.

__global__ __launch_bounds__(256) void u1_kernel(
        const int* __restrict__ s0, const int* __restrict__ d0,
        const int* __restrict__ s1, const int* __restrict__ d1,
        const int* __restrict__ s2, const int* __restrict__ d2,
        int* __restrict__ bcur, unsigned* __restrict__ ebuf,
        const float* __restrict__ Wsrc, const float* __restrict__ Wdst,
        const float* __restrict__ Wfc, const float* __restrict__ Wdim,
        unsigned short* __restrict__ WtRel, unsigned short* __restrict__ WtFc,
        unsigned short* __restrict__ WtDim,
        const float* __restrict__ x, unsigned short* __restrict__ xb) {
    int b = blockIdx.x;
    if (b < HIST_B) {
        int i = b * 256 + threadIdx.x;
        if (i < 3 * E_EDGES) {
            int r = i / E_EDGES;
            int e = i - r * E_EDGES;
            const int* src = (r == 0) ? s0 : ((r == 1) ? s1 : s2);
            const int* dst = (r == 0) ? d0 : ((r == 1) ? d1 : d2);
            int d = dst[e], s = src[e];
            int bk = r * NBUCK + (d >> 6);
            int pos = atomicAdd(&bcur[(size_t)bk * BCSTR], 1);
            if (pos < BCAP)
                ebuf[(size_t)bk * BCAP + pos] = (unsigned)d | ((unsigned)s << 16);
        }
    } else if (b < HIST_B + PACK_B) {
        int i = (b - HIST_B) * 256 + threadIdx.x;
        if (i < PACK_REL) {
            int k = i & 63;
            int n = (i >> 6) & 511;
            int lr = i >> 15;
            const float* srcm = (n < 256) ? Wsrc : Wdst;
            WtRel[i] = f2bf(srcm[((size_t)lr * 64 + k) * 256 + (n & 255)]);
        } else if (i < PACK_REL + PACK_FC) {
            int j = i - PACK_REL;
            int l = j >> 12, rem = j & 4095;
            int k = rem & 63, n = rem >> 6;
            WtFc[j] = f2bf(Wfc[(size_t)l * 4096 + k * 64 + n]);
        } else if (i < PACK_REL + PACK_FC + PACK_DIM) {
            int j = i - PACK_REL - PACK_FC;
            int k = j & 63, n = j >> 6;
            WtDim[j] = f2bf(Wdim[(size_t)k * 256 + n]);
        }
    } else {
        int i = ((b - HIST_B - PACK_B) * 256 + threadIdx.x) * 4;
        if (i < N_NODES * HID) {
            float4 v = *(const float4*)(x + i);
            uint2 o;
            o.x = (unsigned)f2bf(v.x) | ((unsigned)f2bf(v.y) << 16);
            o.y = (unsigned)f2bf(v.z) | ((unsigned)f2bf(v.w) << 16);
            *(uint2*)(xb + i) = o;
        }
    }
}

// ------------------- bucket scan: bstart = prefix(bucket sizes) --------------
// 3 blocks (one per relation), 1024 threads; NBUCK=782 fits one block.

__global__ __launch_bounds__(1024) void bscan_kernel(const int* __restrict__ bcur,
                                                     int* __restrict__ bstart,
                                                     int* __restrict__ row_off) {
    __shared__ int A[1024], B[1024];
    int tid = threadIdx.x;
    int r = blockIdx.x;
    int v = (tid < NBUCK) ? bcur[(size_t)(r * NBUCK + tid) * BCSTR] : 0;
    if (v > BCAP) v = BCAP;
    A[tid] = v;
    __syncthreads();
    int* s = A; int* d = B;
    for (int o = 1; o < 1024; o <<= 1) {
        int x = s[tid];
        if (tid >= o) x += s[tid - o];
        d[tid] = x;
        __syncthreads();
        int* t = s; s = d; d = t;
    }
    if (tid < NBUCK) bstart[r * NBUCK + tid] = s[tid] - v;   // exclusive prefix
    if (tid == 0) row_off[(size_t)r * (N_NODES + 1) + N_NODES] = E_EDGES;
}

// --------------------------- MFMA projection body ----------------------------
// One block per (node-block px, relation). B-fragments (hB rows, node side)
// are loaded ONCE into registers and reused across all 8 feature blocks.
// Per py: 8 MFMA -> padded LDS tile -> full-128B-line sweep to out.

static __device__ __forceinline__ void proj_body8(int bx,
        const unsigned short* __restrict__ hB, const unsigned short* __restrict__ Wt,
        unsigned short* __restrict__ out, int M, unsigned short* tile) {
    int tid = threadIdx.x;
    int wave = tid >> 6, lane = tid & 63;
    int q = lane >> 4, li = lane & 15;
    int nodeLoc = (wave >> 1) * 32;
    int featLoc = (wave & 1) * 32;
    int nodeBase = bx * 64 + nodeLoc;

    // B-fragments: loaded once, reused for all 8 py iterations
    bf16x8 bfr[2][2];
    #pragma unroll
    for (int t = 0; t < 2; ++t) {
        int node = nodeBase + t * 16 + li; if (node >= M) node = M - 1;
        const unsigned short* bp = hB + (size_t)node * 64 + q * 8;
        #pragma unroll
        for (int s = 0; s < 2; ++s) bfr[t][s] = *(const bf16x8*)(bp + s * 32);
    }

    #pragma unroll
    for (int py = 0; py < 8; ++py) {
        int featBase = py * 64 + featLoc;
        bf16x8 afr[2][2];
        #pragma unroll
        for (int t = 0; t < 2; ++t) {
            const unsigned short* ap = Wt + (size_t)(featBase + t * 16 + li) * 64 + q * 8;
            #pragma unroll
            for (int s = 0; s < 2; ++s) afr[t][s] = *(const bf16x8*)(ap + s * 32);
        }
        f32x4 acc[2][2];
        #pragma unroll
        for (int a = 0; a < 2; ++a)
            #pragma unroll
            for (int bq = 0; bq < 2; ++bq)
                #pragma unroll
                for (int i = 0; i < 4; ++i) acc[a][bq][i] = 0.f;
        #pragma unroll
        for (int s = 0; s < 2; ++s)
            #pragma unroll
            for (int ft = 0; ft < 2; ++ft)
                #pragma unroll
                for (int nt = 0; nt < 2; ++nt)
                    acc[ft][nt] = __builtin_amdgcn_mfma_f32_16x16x32_bf16(afr[ft][s], bfr[nt][s], acc[ft][nt], 0, 0, 0);

        // stage this 64x64 tile to LDS (local coords)
        #pragma unroll
        for (int ft = 0; ft < 2; ++ft) {
            int fl = featLoc + ft * 16 + q * 4;
            #pragma unroll
            for (int nt = 0; nt < 2; ++nt) {
                int nl = nodeLoc + nt * 16 + li;
                unsigned lo = (unsigned)f2bf(acc[ft][nt][0]) | ((unsigned)f2bf(acc[ft][nt][1]) << 16);
                unsigned hi = (unsigned)f2bf(acc[ft][nt][2]) | ((unsigned)f2bf(acc[ft][nt][3]) << 16);
                uint2 pk; pk.x = lo; pk.y = hi;
                *(uint2*)(tile + nl * TS + fl) = pk;
            }
        }
        __syncthreads();
        // coalesced sweep: 8 lanes cover one node's 128B chunk, full-line stores
        #pragma unroll
        for (int p = 0; p < 2; ++p) {
            int idx = p * 256 + tid;          // 0..511
            int nl = idx >> 3, sg = idx & 7;
            int node = bx * 64 + nl;
            if (node < M) {
                uint4 v = *(const uint4*)(tile + nl * TS + sg * 8);
                *(uint4*)(out + (size_t)node * 512 + py * 64 + sg * 8) = v;
            }
        }
        __syncthreads();    // tile reused next py
    }
}

// ------- U2b: CSR pass 2 (bucket-local, LDS count/scan/place) ∪ proj ---------
// One block per bucket: count its <=512 edges into 64 LDS counters, wave-scan
// to per-node offsets, write row_off for its 64 nodes, then place edges into
// csr_src via LDS cursors. No global cursor atomics at all.

__global__ __launch_bounds__(256) void u2b_kernel(
        const int* __restrict__ bstart, const int* __restrict__ bcur,
        const unsigned* __restrict__ ebuf, int* __restrict__ csr_src,
        int* __restrict__ row_off,
        const unsigned short* __restrict__ xb, const unsigned short* __restrict__ WtRel0,
        unsigned short* __restrict__ p0, unsigned short* __restrict__ p1,
        unsigned short* __restrict__ p2) {
    __shared__ __align__(16) unsigned short tile[64 * TS];
    __shared__ int cnt64[64], cur64[64];
    int b = blockIdx.x;
    int tid = threadIdx.x;
    if (b < P2_B) {
        int r = b / NBUCK, bk = b - r * NBUCK;
        int n0 = bk << 6;
        int base = bstart[r * NBUCK + bk];
        int cnt = bcur[(size_t)(r * NBUCK + bk) * BCSTR];
        if (cnt > BCAP) cnt = BCAP;
        if (tid < 64) cnt64[tid] = 0;
        __syncthreads();
        const unsigned* eb = ebuf + (size_t)(r * NBUCK + bk) * BCAP;
        for (int t = tid; t < cnt; t += 256)
            atomicAdd(&cnt64[(eb[t] & 0xffff) - n0], 1);
        __syncthreads();
        if (tid < 64) {
            int x = cnt64[tid];
            int incl = x;
            #pragma unroll
            for (int o = 1; o < 64; o <<= 1) {
                int y = __shfl_up(incl, o, 64);
                if (tid >= o) incl += y;
            }
            int excl = incl - x;
            cur64[tid] = excl;
            int node = n0 + tid;
            if (node < N_NODES)
                row_off[(size_t)r * (N_NODES + 1) + node] = base + excl;
        }
        __syncthreads();
        int* cs = csr_src + (size_t)r * E_EDGES + base;
        for (int t = tid; t < cnt; t += 256) {
            unsigned v = eb[t];
            int d = (v & 0xffff) - n0;
            int s = (int)(v >> 16);
            int pos = atomicAdd(&cur64[d], 1);
            cs[pos] = s;
        }
    } else {
        int b2 = b - P2_B;
        int px = b2 % GX;
        int pz = b2 / GX;
        unsigned short* out = (pz == 0) ? p0 : ((pz == 1) ? p1 : p2);
        proj_body8(px, xb, WtRel0 + (size_t)pz * 512 * 64, out, N_NODES, tile);
    }
}

// proj for layer 1 (no CSR work to overlap)
__global__ __launch_bounds__(256) void gemm_proj3(const unsigned short* __restrict__ hB,
                                                  const unsigned short* __restrict__ WtL,
                                                  unsigned short* __restrict__ p0,
                                                  unsigned short* __restrict__ p1,
                                                  unsigned short* __restrict__ p2,
                                                  int M) {
    __shared__ __align__(16) unsigned short tile[64 * TS];
    int r = blockIdx.z;
    unsigned short* out = (r == 0) ? p0 : ((r == 1) ? p1 : p2);
    proj_body8(blockIdx.x, hB, WtL + (size_t)r * 512 * 64, out, M, tile);
}

__global__ __launch_bounds__(256) void gemm_f32out(const unsigned short* __restrict__ hB,
                                                   const unsigned short* __restrict__ Wt,
                                                   const float* __restrict__ bias,
                                                   float* __restrict__ out,
                                                   int M, int Nout, int relu) {
    int tid = threadIdx.x;
    int wave = tid >> 6, lane = tid & 63;
    int q = lane >> 4, li = lane & 15;
    int nodeBase = blockIdx.x * 64 + (wave >> 1) * 32;
    int featBase = blockIdx.y * 64 + (wave & 1) * 32;

    const unsigned short* aptr[2];
    const unsigned short* bptr[2];
    #pragma unroll
    for (int t = 0; t < 2; ++t) {
        aptr[t] = Wt + (size_t)(featBase + t * 16 + li) * 64 + q * 8;
        int node = nodeBase + t * 16 + li; if (node >= M) node = M - 1;
        bptr[t] = hB + (size_t)node * 64 + q * 8;
    }
    f32x4 acc[2][2];
    #pragma unroll
    for (int a = 0; a < 2; ++a)
        #pragma unroll
        for (int bq = 0; bq < 2; ++bq)
            #pragma unroll
            for (int i = 0; i < 4; ++i) acc[a][bq][i] = 0.f;

    #pragma unroll
    for (int s = 0; s < 2; ++s) {
        bf16x8 a[2], b[2];
        #pragma unroll
        for (int t = 0; t < 2; ++t) {
            a[t] = *(const bf16x8*)(aptr[t] + s * 32);
            b[t] = *(const bf16x8*)(bptr[t] + s * 32);
        }
        #pragma unroll
        for (int ft = 0; ft < 2; ++ft)
            #pragma unroll
            for (int nt = 0; nt < 2; ++nt)
                acc[ft][nt] = __builtin_amdgcn_mfma_f32_16x16x32_bf16(a[ft], b[nt], acc[ft][nt], 0, 0, 0);
    }
    #pragma unroll
    for (int ft = 0; ft < 2; ++ft) {
        int f0 = featBase + ft * 16 + q * 4;
        float b0 = bias[f0], b1 = bias[f0 + 1], b2 = bias[f0 + 2], b3 = bias[f0 + 3];
        #pragma unroll
        for (int nt = 0; nt < 2; ++nt) {
            int node = nodeBase + nt * 16 + li;
            if (node >= M) continue;
            float4 o;
            o.x = acc[ft][nt][0] + b0; o.y = acc[ft][nt][1] + b1;
            o.z = acc[ft][nt][2] + b2; o.w = acc[ft][nt][3] + b3;
            if (relu) {
                o.x = fmaxf(o.x, 0.f); o.y = fmaxf(o.y, 0.f);
                o.z = fmaxf(o.z, 0.f); o.w = fmaxf(o.w, 0.f);
            }
            *(float4*)(out + (size_t)node * Nout + f0) = o;
        }
    }
}

// ----------------- fused attention: 3 relations + head-mean ------------------
// One wave per dst node. proj row: [fs(256) | fd(256)] bf16. Softmax without
// max-shift (|logit| clamped); fd pre-scaled by SCALE*log2e.
// All three rels' dependent chains issued in parallel straight-line (round-5
// structure, proven 90us): 3x row_off pairs -> 3x index vectors -> 3x fd +
// 3x up-to-8 row gathers -> process rel-by-rel. Heavy rows: serial tail.

#define AGG_ISSUE8(R, sv, j0, cnt, proj) do {                                   \
    _Pragma("unroll")                                                           \
    for (int t_ = 0; t_ < 8; ++t_) {                                            \
        if (t_ < (cnt)) {                                                       \
            int idx_ = __shfl((sv), (j0) + t_, 64);                             \
            (R)[t_] = *(const uint2*)((proj) + (size_t)idx_ * 512 + lane * 4);  \
        }                                                                       \
    }                                                                           \
} while (0)

#define AGG_PROC8(R, cnt) do {                                                  \
    _Pragma("unroll")                                                           \
    for (int t_ = 0; t_ < 8; ++t_) {                                            \
        if (t_ < (cnt)) {                                                       \
            float s0_ = __uint_as_float((R)[t_].x << 16);                       \
            float s1_ = __uint_as_float((R)[t_].x & 0xffff0000u);               \
            float s2_ = __uint_as_float((R)[t_].y << 16);                       \
            float s3_ = __uint_as_float((R)[t_].y & 0xffff0000u);               \
            float p_ = s0_ * fd0_ + s1_ * fd1_ + s2_ * fd2_ + s3_ * fd3_;       \
            p_ = rowsum16(p_);                                                  \
            p_ = fminf(fmaxf(p_, -60.f), 60.f);                                 \
            float pe_ = __builtin_amdgcn_exp2f(p_);                             \
            den_ += pe_;                                                        \
            a0_ += pe_ * s0_; a1_ += pe_ * s1_;                                 \
            a2_ += pe_ * s2_; a3_ += pe_ * s3_;                                 \
        }                                                                       \
    }                                                                           \
} while (0)

// process one relation: consume prefetched rv[0..cB), then serial tail.
#define AGG_REL(proj, fdr, sv, deg, cs, rv, cB) do {                            \
    if ((deg) > 0) {                                                            \
        float fd0_ = bf2f((fdr).x & 0xffff) * FS;                               \
        float fd1_ = __uint_as_float((fdr).x & 0xffff0000u) * FS;               \
        float fd2_ = bf2f((fdr).y & 0xffff) * FS;                               \
        float fd3_ = __uint_as_float((fdr).y & 0xffff0000u) * FS;               \
        float den_ = 0.f, a0_ = 0.f, a1_ = 0.f, a2_ = 0.f, a3_ = 0.f;           \
        AGG_PROC8(rv, cB);                                                      \
        int e_ = (cB);                                                          \
        int sv_ = (sv);                                                         \
        while (e_ < (deg)) {                                                    \
            if ((e_ & 63) == 0) {                                               \
                int o_ = e_ + lane;                                             \
                sv_ = (o_ < (deg)) ? (cs)[o_] : 0;                              \
            }                                                                   \
            int nt_ = (deg) - e_; if (nt_ > 8) nt_ = 8;                         \
            uint2 rt_[8];                                                       \
            AGG_ISSUE8(rt_, sv_, (e_ & 63), nt_, proj);                         \
            AGG_PROC8(rt_, nt_);                                                \
            e_ += nt_;                                                          \
        }                                                                       \
        float inv_ = 1.0f / fmaxf(den_, 1e-9f);                                 \
        t0 += a0_ * inv_; t1 += a1_ * inv_;                                     \
        t2 += a2_ * inv_; t3 += a3_ * inv_;                                     \
    }                                                                           \
} while (0)

__global__ __launch_bounds__(256) void agg_fused(const int* __restrict__ row_off,
                                                 const int* __restrict__ csr_src,
                                                 const unsigned short* __restrict__ p0,
                                                 const unsigned short* __restrict__ p1,
                                                 const unsigned short* __restrict__ p2,
                                                 unsigned short* __restrict__ hm) {
    int wave = (blockIdx.x * 256 + threadIdx.x) >> 6;
    int lane = threadIdx.x & 63;
    if (wave >= N_NODES) return;
    int dst = wave;
    const float FS = ATT_SCALE * LOG2E;

    // --- phase 0: all row_off pairs (6 independent loads) ---
    const int* ro0 = row_off;
    const int* ro1 = row_off + (N_NODES + 1);
    const int* ro2 = row_off + 2 * (N_NODES + 1);
    int b0 = ro0[dst], e0 = ro0[dst + 1];
    int b1 = ro1[dst], e1 = ro1[dst + 1];
    int b2 = ro2[dst], e2 = ro2[dst + 1];
    // fd rows (independent, unconditional)
    uint2 fdr0 = *(const uint2*)(p0 + (size_t)dst * 512 + 256 + lane * 4);
    uint2 fdr1 = *(const uint2*)(p1 + (size_t)dst * 512 + 256 + lane * 4);
    uint2 fdr2 = *(const uint2*)(p2 + (size_t)dst * 512 + 256 + lane * 4);
    int deg0 = e0 - b0, deg1 = e1 - b1, deg2 = e2 - b2;

    // --- phase 1: index vectors for all three rels ---
    const int* cs0 = csr_src + b0;
    const int* cs1 = csr_src + E_EDGES + b1;
    const int* cs2 = csr_src + 2 * E_EDGES + b2;
    int sv0 = (lane < deg0) ? cs0[lane] : 0;
    int sv1 = (lane < deg1) ? cs1[lane] : 0;
    int sv2 = (lane < deg2) ? cs2[lane] : 0;

    // --- phase 2: first up-to-8 row gathers per rel, all in flight ---
    uint2 rv0[8], rv1[8], rv2[8];
    int c0 = deg0 < 8 ? deg0 : 8;
    int c1 = deg1 < 8 ? deg1 : 8;
    int c2 = deg2 < 8 ? deg2 : 8;
    AGG_ISSUE8(rv0, sv0, 0, c0, p0);
    AGG_ISSUE8(rv1, sv1, 0, c1, p1);
    AGG_ISSUE8(rv2, sv2, 0, c2, p2);

    // --- phase 3: process rel-by-rel ---
    float t0 = 0.f, t1 = 0.f, t2 = 0.f, t3 = 0.f;
    AGG_REL(p0, fdr0, sv0, deg0, cs0, rv0, c0);
    AGG_REL(p1, fdr1, sv1, deg1, cs1, rv1, c1);
    AGG_REL(p2, fdr2, sv2, deg2, cs2, rv2, c2);

    // mean over heads: feature f of head h lives at lane h*16 + f/4, slot f&3
    t0 += __shfl_xor(t0, 16, 64); t0 += __shfl_xor(t0, 32, 64);
    t1 += __shfl_xor(t1, 16, 64); t1 += __shfl_xor(t1, 32, 64);
    t2 += __shfl_xor(t2, 16, 64); t2 += __shfl_xor(t2, 32, 64);
    t3 += __shfl_xor(t3, 16, 64); t3 += __shfl_xor(t3, 32, 64);
    if (lane < 16) {
        unsigned lo = (unsigned)f2bf(t0 * 0.25f) | ((unsigned)f2bf(t1 * 0.25f) << 16);
        unsigned hi = (unsigned)f2bf(t2 * 0.25f) | ((unsigned)f2bf(t3 * 0.25f) << 16);
        uint2 pk; pk.x = lo; pk.y = hi;
        *(uint2*)(hm + (size_t)dst * 64 + lane * 4) = pk;
    }
}

// ----------------------------- batchnorm -------------------------------------

__global__ __launch_bounds__(256) void bn_reduce_kernel(const float* __restrict__ y,
                                                        float* __restrict__ acc1,
                                                        float* __restrict__ acc2) {
    int tid = threadIdx.x;
    int c = tid & 63;
    int g = tid >> 6;
    int rowStart = blockIdx.x * 4 + g;
    int stride = gridDim.x * 4;
    float s1 = 0.f, s2 = 0.f;
    for (int r = rowStart; r < N_NODES; r += stride) {
        float v = y[(size_t)r * 64 + c];
        s1 += v; s2 += v * v;
    }
    __shared__ float l1[4][64], l2[4][64];
    l1[g][c] = s1; l2[g][c] = s2;
    __syncthreads();
    if (g == 0) {
        s1 = l1[0][c] + l1[1][c] + l1[2][c] + l1[3][c];
        s2 = l2[0][c] + l2[1][c] + l2[2][c] + l2[3][c];
        atomicAdd(&acc1[c], s1);
        atomicAdd(&acc2[c], s2);
    }
}

__global__ void bn_apply_kernel(const float* __restrict__ y, const float* __restrict__ acc1,
                                const float* __restrict__ acc2, const float* __restrict__ gamma,
                                const float* __restrict__ beta,
                                unsigned short* __restrict__ outb) {
    int i = blockIdx.x * blockDim.x + threadIdx.x;
    if (i >= N_NODES * HID) return;
    int c = i & 63;
    const float invN = 1.0f / (float)N_NODES;
    float mu = acc1[c] * invN;
    float var = acc2[c] * invN - mu * mu;
    float v = gamma[c] * (y[i] - mu) * rsqrtf(var + EPS_BN) + beta[c];
    outb[i] = f2bf(v);
}

// ----------------------------- launch ----------------------------------------

extern "C" void kernel_launch(void* const* d_in, const int* in_sizes, int n_in,
                              void* d_out, int out_size, void* d_ws, size_t ws_size,
                              hipStream_t stream) {
    const float* x     = (const float*)d_in[0];
    const int* srcs[3] = {(const int*)d_in[1], (const int*)d_in[3], (const int*)d_in[5]};
    const int* dsts[3] = {(const int*)d_in[2], (const int*)d_in[4], (const int*)d_in[6]};
    const float* Wsrc  = (const float*)d_in[7];
    const float* Wdst  = (const float*)d_in[8];
    const float* Wfc   = (const float*)d_in[9];
    const float* bfc   = (const float*)d_in[10];
    const float* gamma = (const float*)d_in[11];
    const float* beta  = (const float*)d_in[12];
    const float* Wdim  = (const float*)d_in[13];
    const float* bdim  = (const float*)d_in[14];
    float* out = (float*)d_out;

    char* ws = (char*)d_ws;
    size_t off = 0;
    auto alloc = [&](size_t bytes) -> void* {
        void* p = ws + off;
        off += (bytes + 255) & ~(size_t)255;
        return p;
    };
    // bnacc + bcur contiguous so one memset zeros both
    float* bnacc  = (float*)alloc(256 * 4);                     // [0..127] l0, [128..255] l1
    int* bcur     = (int*)alloc((size_t)3 * NBUCK * BCSTR * 4); // 1 line per counter
    int* bstart   = (int*)alloc((size_t)3 * NBUCK * 4);
    int* row_off  = (int*)alloc((size_t)3 * (N_NODES + 1) * 4);
    int* csr_src  = (int*)alloc((size_t)3 * E_EDGES * 4);
    unsigned* ebuf = (unsigned*)alloc((size_t)3 * NBUCK * BCAP * 4);
    unsigned short* proj0 = (unsigned short*)alloc((size_t)N_NODES * 512 * 2);
    unsigned short* proj1 = (unsigned short*)alloc((size_t)N_NODES * 512 * 2);
    unsigned short* proj2 = (unsigned short*)alloc((size_t)N_NODES * 512 * 2);
    unsigned short* hm    = (unsigned short*)alloc((size_t)N_NODES * HID * 2);
    float* ybuf           = (float*)alloc((size_t)N_NODES * HID * 4);
    unsigned short* xb    = (unsigned short*)alloc((size_t)N_NODES * HID * 2);
    unsigned short* hb0   = (unsigned short*)alloc((size_t)N_NODES * HID * 2);
    unsigned short* hb1   = (unsigned short*)alloc((size_t)N_NODES * HID * 2);
    unsigned short* WtRel = (unsigned short*)alloc((size_t)PACK_REL * 2);
    unsigned short* WtFc  = (unsigned short*)alloc((size_t)PACK_FC * 2);
    unsigned short* WtDim = (unsigned short*)alloc((size_t)PACK_DIM * 2);

    // one memset covers bnacc (1 KB) + bcur (300 KB), contiguous
    hipMemsetAsync(bnacc, 0, 1024 + (size_t)3 * NBUCK * BCSTR * 4, stream);

    // U1: bucket-append ∪ weight-pack ∪ x->bf16 cast
    u1_kernel<<<HIST_B + PACK_B + CVT_B, 256, 0, stream>>>(
        srcs[0], dsts[0], srcs[1], dsts[1], srcs[2], dsts[2],
        bcur, ebuf, Wsrc, Wdst, Wfc, Wdim, WtRel, WtFc, WtDim, x, xb);

    // bucket prefix-sum (3 blocks)
    bscan_kernel<<<3, 1024, 0, stream>>>(bcur, bstart, row_off);

    // U2b: CSR pass 2 (bucket-local count/scan/place, writes row_off) ∪ proj(l0)
    u2b_kernel<<<P2_B + PROJ_B, 256, 0, stream>>>(
        bstart, bcur, ebuf, csr_src, row_off, xb, WtRel, proj0, proj1, proj2);

    unsigned short* hbufs[2] = {hb0, hb1};
    const unsigned short* hcur = xb;
    for (int l = 0; l < L_LAYERS; ++l) {
        if (l > 0) {
            dim3 g(GX, 1, 3);
            gemm_proj3<<<g, 256, 0, stream>>>(hcur, WtRel + (size_t)l * 3 * 512 * 64,
                                              proj0, proj1, proj2, N_NODES);
        }
        agg_fused<<<(N_NODES + 3) / 4, 256, 0, stream>>>(row_off, csr_src,
                                                         proj0, proj1, proj2, hm);
        dim3 g2(GX, 1);
        gemm_f32out<<<g2, 256, 0, stream>>>(hm, WtFc + (size_t)l * 64 * 64, bfc + (size_t)l * HID,
                                            ybuf, N_NODES, 64, 1);
        float* ba = bnacc + l * 128;
        bn_reduce_kernel<<<256, 256, 0, stream>>>(ybuf, ba, ba + 64);
        bn_apply_kernel<<<(N_NODES * HID + 255) / 256, 256, 0, stream>>>(
            ybuf, ba, ba + 64, gamma + (size_t)l * HID, beta + (size_t)l * HID, hbufs[l]);
        hcur = hbufs[l];
    }
    dim3 g3(GX, IN_DIM_ / 64);
    gemm_f32out<<<g3, 256, 0, stream>>>(hcur, WtDim, bdim, out, N_NODES, IN_DIM_, 0);
}

// Round 10
// 475.912 us; speedup vs baseline: 1.1350x; 1.0154x over previous
//
#include <hip/hip_runtime.h>
#include <math.h>

#define N_NODES 50000
#define E_EDGES 250000
#define HID 64
#define L_LAYERS 2
#define IN_DIM_ 256
#define ATT_SCALE 0.125f
#define LOG2E 1.44269504f
#define EPS_BN 1e-5f
#define GX 782          // ceil(50000/64)

#define PACK_REL (6 * 512 * 64)
#define PACK_FC  (2 * 64 * 64)
#define PACK_DIM (256 * 64)
#define HIST_B   2930   // ceil(750000/256)
#define PACK_B   864    // (PACK_REL+PACK_FC+PACK_DIM)/256
#define CVT_B    3125   // 3.2M/4/256
#define PROJ_B   (GX * 3)   // py folded into the block (x8 work per block)

#define NBUCK 782       // ceil(50000/64) buckets per relation (64 nodes/bucket)
#define P2_B  (3 * NBUCK)
#define BCSTR 32        // bucket-cursor stride in ints: one 128B line per counter
#define BCAP  512       // fixed bucket capacity (avg load 320 = Poisson; 512 = +10 sigma)

#define TS 72           // LDS tile row stride in shorts (64 + 8 pad; 144B rows, 16B-aligned)

typedef __attribute__((ext_vector_type(8))) short bf16x8;
typedef __attribute__((ext_vector_type(4))) float f32x4;

static __device__ __forceinline__ unsigned short f2bf(float f) {
    unsigned u = __float_as_uint(f);
    unsigned r = (u + 0x7fff + ((u >> 16) & 1)) >> 16;
    return (unsigned short)r;
}
static __device__ __forceinline__ float bf2f(unsigned u) {
    return __uint_as_float(u << 16);
}

// sum across each 16-lane row via DPP butterfly (4 VALU adds, no LDS)
static __device__ __forceinline__ float rowsum16(float x) {
    int t;
    t = __builtin_amdgcn_update_dpp(0, __float_as_int(x), 0xB1, 0xf, 0xf, true);  // quad_perm(1,0,3,2)
    x += __int_as_float(t);
    t = __builtin_amdgcn_update_dpp(0, __float_as_int(x), 0x4E, 0xf, 0xf, true);  // quad_perm(2,3,0,1)
    x += __int_as_float(t);
    t = __builtin_amdgcn_update_dpp(0, __float_as_int(x), 0x141, 0xf, 0xf, true); // row_half_mirror
    x += __int_as_float(t);
    t = __builtin_amdgcn_update_dpp(0, __float_as_int(x), 0x140, 0xf, 0xf, true); // row_mirror
    x += __int_as_float(t);
    return x;
}

// ------------- U1: bucket-append ∪ weight-pack ∪ x->bf16 cast ----------------
// The bucket-append stream IS the CSR build input: no per-node histogram, no
// 3-phase scan. Each frontier counter owns a 128B line (BCSTR) so bucket
// atomics never share a line. Fixed capacity BCAP/bucket.

__global__ __launch_bounds__(256) void u1_kernel(
        const int* __restrict__ s0, const int* __restrict__ d0,
        const int* __restrict__ s1, const int* __restrict__ d1,
        const int* __restrict__ s2, const int* __restrict__ d2,
        int* __restrict__ bcur, unsigned* __restrict__ ebuf,
        const float* __restrict__ Wsrc, const float* __restrict__ Wdst,
        const float* __restrict__ Wfc, const float* __restrict__ Wdim,
        unsigned short* __restrict__ WtRel, unsigned short* __restrict__ WtFc,
        unsigned short* __restrict__ WtDim,
        const float* __restrict__ x, unsigned short* __restrict__ xb) {
    int b = blockIdx.x;
    if (b < HIST_B) {
        int i = b * 256 + threadIdx.x;
        if (i < 3 * E_EDGES) {
            int r = i / E_EDGES;
            int e = i - r * E_EDGES;
            const int* src = (r == 0) ? s0 : ((r == 1) ? s1 : s2);
            const int* dst = (r == 0) ? d0 : ((r == 1) ? d1 : d2);
            int d = dst[e], s = src[e];
            int bk = r * NBUCK + (d >> 6);
            int pos = atomicAdd(&bcur[(size_t)bk * BCSTR], 1);
            if (pos < BCAP)
                ebuf[(size_t)bk * BCAP + pos] = (unsigned)d | ((unsigned)s << 16);
        }
    } else if (b < HIST_B + PACK_B) {
        int i = (b - HIST_B) * 256 + threadIdx.x;
        if (i < PACK_REL) {
            int k = i & 63;
            int n = (i >> 6) & 511;
            int lr = i >> 15;
            const float* srcm = (n < 256) ? Wsrc : Wdst;
            WtRel[i] = f2bf(srcm[((size_t)lr * 64 + k) * 256 + (n & 255)]);
        } else if (i < PACK_REL + PACK_FC) {
            int j = i - PACK_REL;
            int l = j >> 12, rem = j & 4095;
            int k = rem & 63, n = rem >> 6;
            WtFc[j] = f2bf(Wfc[(size_t)l * 4096 + k * 64 + n]);
        } else if (i < PACK_REL + PACK_FC + PACK_DIM) {
            int j = i - PACK_REL - PACK_FC;
            int k = j & 63, n = j >> 6;
            WtDim[j] = f2bf(Wdim[(size_t)k * 256 + n]);
        }
    } else {
        int i = ((b - HIST_B - PACK_B) * 256 + threadIdx.x) * 4;
        if (i < N_NODES * HID) {
            float4 v = *(const float4*)(x + i);
            uint2 o;
            o.x = (unsigned)f2bf(v.x) | ((unsigned)f2bf(v.y) << 16);
            o.y = (unsigned)f2bf(v.z) | ((unsigned)f2bf(v.w) << 16);
            *(uint2*)(xb + i) = o;
        }
    }
}

// ------------------- bucket scan: bstart = prefix(bucket sizes) --------------

__global__ __launch_bounds__(1024) void bscan_kernel(const int* __restrict__ bcur,
                                                     int* __restrict__ bstart,
                                                     int* __restrict__ row_off) {
    __shared__ int A[1024], B[1024];
    int tid = threadIdx.x;
    int r = blockIdx.x;
    int v = (tid < NBUCK) ? bcur[(size_t)(r * NBUCK + tid) * BCSTR] : 0;
    if (v > BCAP) v = BCAP;
    A[tid] = v;
    __syncthreads();
    int* s = A; int* d = B;
    for (int o = 1; o < 1024; o <<= 1) {
        int x = s[tid];
        if (tid >= o) x += s[tid - o];
        d[tid] = x;
        __syncthreads();
        int* t = s; s = d; d = t;
    }
    if (tid < NBUCK) bstart[r * NBUCK + tid] = s[tid] - v;   // exclusive prefix
    if (tid == 0) row_off[(size_t)r * (N_NODES + 1) + N_NODES] = E_EDGES;
}

// --------------------------- MFMA projection core ----------------------------
// B-fragments (node side) are built by the CALLER (bf16-direct or f32+BN) and
// reused across all 8 feature blocks. Per py: 8 MFMA -> padded LDS tile ->
// full-128B-line sweep to out.

static __device__ __forceinline__ void proj_core(int bx, const bf16x8 bfr[2][2],
        const unsigned short* __restrict__ Wt,
        unsigned short* __restrict__ out, int M, unsigned short* tile) {
    int tid = threadIdx.x;
    int wave = tid >> 6, lane = tid & 63;
    int q = lane >> 4, li = lane & 15;
    int nodeLoc = (wave >> 1) * 32;
    int featLoc = (wave & 1) * 32;

    #pragma unroll
    for (int py = 0; py < 8; ++py) {
        int featBase = py * 64 + featLoc;
        bf16x8 afr[2][2];
        #pragma unroll
        for (int t = 0; t < 2; ++t) {
            const unsigned short* ap = Wt + (size_t)(featBase + t * 16 + li) * 64 + q * 8;
            #pragma unroll
            for (int s = 0; s < 2; ++s) afr[t][s] = *(const bf16x8*)(ap + s * 32);
        }
        f32x4 acc[2][2];
        #pragma unroll
        for (int a = 0; a < 2; ++a)
            #pragma unroll
            for (int bq = 0; bq < 2; ++bq)
                #pragma unroll
                for (int i = 0; i < 4; ++i) acc[a][bq][i] = 0.f;
        #pragma unroll
        for (int s = 0; s < 2; ++s)
            #pragma unroll
            for (int ft = 0; ft < 2; ++ft)
                #pragma unroll
                for (int nt = 0; nt < 2; ++nt)
                    acc[ft][nt] = __builtin_amdgcn_mfma_f32_16x16x32_bf16(afr[ft][s], bfr[nt][s], acc[ft][nt], 0, 0, 0);

        // stage this 64x64 tile to LDS (local coords)
        #pragma unroll
        for (int ft = 0; ft < 2; ++ft) {
            int fl = featLoc + ft * 16 + q * 4;
            #pragma unroll
            for (int nt = 0; nt < 2; ++nt) {
                int nl = nodeLoc + nt * 16 + li;
                unsigned lo = (unsigned)f2bf(acc[ft][nt][0]) | ((unsigned)f2bf(acc[ft][nt][1]) << 16);
                unsigned hi = (unsigned)f2bf(acc[ft][nt][2]) | ((unsigned)f2bf(acc[ft][nt][3]) << 16);
                uint2 pk; pk.x = lo; pk.y = hi;
                *(uint2*)(tile + nl * TS + fl) = pk;
            }
        }
        __syncthreads();
        // coalesced sweep: 8 lanes cover one node's 128B chunk, full-line stores
        #pragma unroll
        for (int p = 0; p < 2; ++p) {
            int idx = p * 256 + tid;          // 0..511
            int nl = idx >> 3, sg = idx & 7;
            int node = bx * 64 + nl;
            if (node < M) {
                uint4 v = *(const uint4*)(tile + nl * TS + sg * 8);
                *(uint4*)(out + (size_t)node * 512 + py * 64 + sg * 8) = v;
            }
        }
        __syncthreads();    // tile reused next py
    }
}

// B-fragment loader: bf16 rows direct (layer 0, from xb)
static __device__ __forceinline__ void load_bfr_bf16(int bx,
        const unsigned short* __restrict__ hB, int M, bf16x8 bfr[2][2]) {
    int tid = threadIdx.x;
    int wave = tid >> 6, lane = tid & 63;
    int q = lane >> 4, li = lane & 15;
    int nodeBase = bx * 64 + (wave >> 1) * 32;
    #pragma unroll
    for (int t = 0; t < 2; ++t) {
        int node = nodeBase + t * 16 + li; if (node >= M) node = M - 1;
        const unsigned short* bp = hB + (size_t)node * 64 + q * 8;
        #pragma unroll
        for (int s = 0; s < 2; ++s) bfr[t][s] = *(const bf16x8*)(bp + s * 32);
    }
}

// B-fragment loader: f32 rows + fused batchnorm (y*a + b), a/b from LDS
static __device__ __forceinline__ void load_bfr_bn(int bx,
        const float* __restrict__ y, int M,
        const float* s_a, const float* s_b, bf16x8 bfr[2][2]) {
    int tid = threadIdx.x;
    int wave = tid >> 6, lane = tid & 63;
    int q = lane >> 4, li = lane & 15;
    int nodeBase = bx * 64 + (wave >> 1) * 32;
    #pragma unroll
    for (int t = 0; t < 2; ++t) {
        int node = nodeBase + t * 16 + li; if (node >= M) node = M - 1;
        const float* bp = y + (size_t)node * 64 + q * 8;
        #pragma unroll
        for (int s = 0; s < 2; ++s) {
            int fb = q * 8 + s * 32;
            float4 u0 = *(const float4*)(bp + s * 32);
            float4 u1 = *(const float4*)(bp + s * 32 + 4);
            bf16x8 v;
            v[0] = (short)f2bf(u0.x * s_a[fb + 0] + s_b[fb + 0]);
            v[1] = (short)f2bf(u0.y * s_a[fb + 1] + s_b[fb + 1]);
            v[2] = (short)f2bf(u0.z * s_a[fb + 2] + s_b[fb + 2]);
            v[3] = (short)f2bf(u0.w * s_a[fb + 3] + s_b[fb + 3]);
            v[4] = (short)f2bf(u1.x * s_a[fb + 4] + s_b[fb + 4]);
            v[5] = (short)f2bf(u1.y * s_a[fb + 5] + s_b[fb + 5]);
            v[6] = (short)f2bf(u1.z * s_a[fb + 6] + s_b[fb + 6]);
            v[7] = (short)f2bf(u1.w * s_a[fb + 7] + s_b[fb + 7]);
            bfr[t][s] = v;
        }
    }
}

// BN param table: a = gamma*rstd, b = beta - mu*a (64 feats into LDS)
#define BN_PREAMBLE(stats, gamma, beta, s_a, s_b) do {                          \
    int tid_ = threadIdx.x;                                                     \
    if (tid_ < 64) {                                                            \
        float s1_ = 0.f, s2_ = 0.f;                                             \
        _Pragma("unroll")                                                       \
        for (int c_ = 0; c_ < 8; ++c_) {                                        \
            s1_ += (stats)[c_ * 128 + tid_];                                    \
            s2_ += (stats)[c_ * 128 + 64 + tid_];                               \
        }                                                                       \
        float mu_ = s1_ * (1.f / N_NODES);                                      \
        float var_ = s2_ * (1.f / N_NODES) - mu_ * mu_;                         \
        float a_ = (gamma)[tid_] * rsqrtf(var_ + EPS_BN);                       \
        (s_a)[tid_] = a_; (s_b)[tid_] = (beta)[tid_] - mu_ * a_;                \
    }                                                                           \
    __syncthreads();                                                            \
} while (0)

// ------- U2b: CSR build (bucket-local, LDS count/scan/place) ∪ proj(l0) ------

__global__ __launch_bounds__(256) void u2b_kernel(
        const int* __restrict__ bstart, const int* __restrict__ bcur,
        const unsigned* __restrict__ ebuf, int* __restrict__ csr_src,
        int* __restrict__ row_off,
        const unsigned short* __restrict__ xb, const unsigned short* __restrict__ WtRel0,
        unsigned short* __restrict__ p0, unsigned short* __restrict__ p1,
        unsigned short* __restrict__ p2) {
    __shared__ __align__(16) unsigned short tile[64 * TS];
    __shared__ int cnt64[64], cur64[64];
    int b = blockIdx.x;
    int tid = threadIdx.x;
    if (b < P2_B) {
        int r = b / NBUCK, bk = b - r * NBUCK;
        int n0 = bk << 6;
        int base = bstart[r * NBUCK + bk];
        int cnt = bcur[(size_t)(r * NBUCK + bk) * BCSTR];
        if (cnt > BCAP) cnt = BCAP;
        if (tid < 64) cnt64[tid] = 0;
        __syncthreads();
        const unsigned* eb = ebuf + (size_t)(r * NBUCK + bk) * BCAP;
        for (int t = tid; t < cnt; t += 256)
            atomicAdd(&cnt64[(eb[t] & 0xffff) - n0], 1);
        __syncthreads();
        if (tid < 64) {
            int x = cnt64[tid];
            int incl = x;
            #pragma unroll
            for (int o = 1; o < 64; o <<= 1) {
                int y = __shfl_up(incl, o, 64);
                if (tid >= o) incl += y;
            }
            int excl = incl - x;
            cur64[tid] = excl;
            int node = n0 + tid;
            if (node < N_NODES)
                row_off[(size_t)r * (N_NODES + 1) + node] = base + excl;
        }
        __syncthreads();
        int* cs = csr_src + (size_t)r * E_EDGES + base;
        for (int t = tid; t < cnt; t += 256) {
            unsigned v = eb[t];
            int d = (v & 0xffff) - n0;
            int s = (int)(v >> 16);
            int pos = atomicAdd(&cur64[d], 1);
            cs[pos] = s;
        }
    } else {
        int b2 = b - P2_B;
        int px = b2 % GX;
        int pz = b2 / GX;
        unsigned short* out = (pz == 0) ? p0 : ((pz == 1) ? p1 : p2);
        bf16x8 bfr[2][2];
        load_bfr_bf16(px, xb, N_NODES, bfr);
        proj_core(px, bfr, WtRel0 + (size_t)pz * 512 * 64, out, N_NODES, tile);
    }
}

// proj for layer 1: fused BN-apply on the B side (reads ybuf f32 + stats)
__global__ __launch_bounds__(256) void proj_bn_kernel(
        const float* __restrict__ y, const float* __restrict__ stats,
        const float* __restrict__ gamma, const float* __restrict__ beta,
        const unsigned short* __restrict__ WtL,
        unsigned short* __restrict__ p0, unsigned short* __restrict__ p1,
        unsigned short* __restrict__ p2, int M) {
    __shared__ __align__(16) unsigned short tile[64 * TS];
    __shared__ float s_a[64], s_b[64];
    BN_PREAMBLE(stats, gamma, beta, s_a, s_b);
    bf16x8 bfr[2][2];
    load_bfr_bn(blockIdx.x, y, M, s_a, s_b, bfr);
    int r = blockIdx.z;
    unsigned short* out = (r == 0) ? p0 : ((r == 1) ? p1 : p2);
    proj_core(blockIdx.x, bfr, WtL + (size_t)r * 512 * 64, out, M, tile);
}

// ---------------- fc GEMM + bias + relu + fused BN statistics ----------------
// Writes y (f32) and accumulates per-feature sum/sumsq into XCD-privatized
// stats[8][128] (copy = blockIdx&7): bn_reduce kernel eliminated.

__global__ __launch_bounds__(256) void fc_bn_kernel(
        const unsigned short* __restrict__ hB,
        const unsigned short* __restrict__ Wt,
        const float* __restrict__ bias,
        float* __restrict__ y, float* __restrict__ stats, int M) {
    int tid = threadIdx.x;
    int wave = tid >> 6, lane = tid & 63;
    int q = lane >> 4, li = lane & 15;
    int nodeBase = blockIdx.x * 64 + (wave >> 1) * 32;
    int featBase = (wave & 1) * 32;

    const unsigned short* aptr[2];
    const unsigned short* bptr[2];
    #pragma unroll
    for (int t = 0; t < 2; ++t) {
        aptr[t] = Wt + (size_t)(featBase + t * 16 + li) * 64 + q * 8;
        int node = nodeBase + t * 16 + li; if (node >= M) node = M - 1;
        bptr[t] = hB + (size_t)node * 64 + q * 8;
    }
    f32x4 acc[2][2];
    #pragma unroll
    for (int a = 0; a < 2; ++a)
        #pragma unroll
        for (int bq = 0; bq < 2; ++bq)
            #pragma unroll
            for (int i = 0; i < 4; ++i) acc[a][bq][i] = 0.f;

    #pragma unroll
    for (int s = 0; s < 2; ++s) {
        bf16x8 a[2], b[2];
        #pragma unroll
        for (int t = 0; t < 2; ++t) {
            a[t] = *(const bf16x8*)(aptr[t] + s * 32);
            b[t] = *(const bf16x8*)(bptr[t] + s * 32);
        }
        #pragma unroll
        for (int ft = 0; ft < 2; ++ft)
            #pragma unroll
            for (int nt = 0; nt < 2; ++nt)
                acc[ft][nt] = __builtin_amdgcn_mfma_f32_16x16x32_bf16(a[ft], b[nt], acc[ft][nt], 0, 0, 0);
    }
    float st1[2][4] = {{0.f,0.f,0.f,0.f},{0.f,0.f,0.f,0.f}};
    float st2[2][4] = {{0.f,0.f,0.f,0.f},{0.f,0.f,0.f,0.f}};
    #pragma unroll
    for (int ft = 0; ft < 2; ++ft) {
        int f0 = featBase + ft * 16 + q * 4;
        float b0 = bias[f0], b1 = bias[f0 + 1], b2 = bias[f0 + 2], b3 = bias[f0 + 3];
        #pragma unroll
        for (int nt = 0; nt < 2; ++nt) {
            int node = nodeBase + nt * 16 + li;
            float4 o;
            o.x = fmaxf(acc[ft][nt][0] + b0, 0.f);
            o.y = fmaxf(acc[ft][nt][1] + b1, 0.f);
            o.z = fmaxf(acc[ft][nt][2] + b2, 0.f);
            o.w = fmaxf(acc[ft][nt][3] + b3, 0.f);
            if (node < M) {
                *(float4*)(y + (size_t)node * 64 + f0) = o;
                st1[ft][0] += o.x; st1[ft][1] += o.y; st1[ft][2] += o.z; st1[ft][3] += o.w;
                st2[ft][0] += o.x * o.x; st2[ft][1] += o.y * o.y;
                st2[ft][2] += o.z * o.z; st2[ft][3] += o.w * o.w;
            }
        }
    }
    #pragma unroll
    for (int ft = 0; ft < 2; ++ft)
        #pragma unroll
        for (int j = 0; j < 4; ++j) {
            st1[ft][j] = rowsum16(st1[ft][j]);
            st2[ft][j] = rowsum16(st2[ft][j]);
        }
    if (li == 0) {
        float* st = stats + (blockIdx.x & 7) * 128;
        #pragma unroll
        for (int ft = 0; ft < 2; ++ft) {
            int f0 = featBase + ft * 16 + q * 4;
            #pragma unroll
            for (int j = 0; j < 4; ++j) {
                atomicAdd(&st[f0 + j], st1[ft][j]);
                atomicAdd(&st[64 + f0 + j], st2[ft][j]);
            }
        }
    }
}

// ------------- final GEMM (256-wide), by-folded, fused BN on B ---------------

__global__ __launch_bounds__(256) void gemm_fin_bn(
        const float* __restrict__ y, const float* __restrict__ stats,
        const float* __restrict__ gamma, const float* __restrict__ beta,
        const unsigned short* __restrict__ Wt, const float* __restrict__ bias,
        float* __restrict__ out, int M) {
    __shared__ float s_a[64], s_b[64];
    BN_PREAMBLE(stats, gamma, beta, s_a, s_b);
    int tid = threadIdx.x;
    int wave = tid >> 6, lane = tid & 63;
    int q = lane >> 4, li = lane & 15;
    int nodeBase = blockIdx.x * 64 + (wave >> 1) * 32;

    bf16x8 bfr[2][2];
    load_bfr_bn(blockIdx.x, y, M, s_a, s_b, bfr);

    #pragma unroll
    for (int by = 0; by < 4; ++by) {
        int featBase = by * 64 + (wave & 1) * 32;
        bf16x8 afr[2][2];
        #pragma unroll
        for (int t = 0; t < 2; ++t) {
            const unsigned short* ap = Wt + (size_t)(featBase + t * 16 + li) * 64 + q * 8;
            #pragma unroll
            for (int s = 0; s < 2; ++s) afr[t][s] = *(const bf16x8*)(ap + s * 32);
        }
        f32x4 acc[2][2];
        #pragma unroll
        for (int a = 0; a < 2; ++a)
            #pragma unroll
            for (int bq = 0; bq < 2; ++bq)
                #pragma unroll
                for (int i = 0; i < 4; ++i) acc[a][bq][i] = 0.f;
        #pragma unroll
        for (int s = 0; s < 2; ++s)
            #pragma unroll
            for (int ft = 0; ft < 2; ++ft)
                #pragma unroll
                for (int nt = 0; nt < 2; ++nt)
                    acc[ft][nt] = __builtin_amdgcn_mfma_f32_16x16x32_bf16(afr[ft][s], bfr[nt][s], acc[ft][nt], 0, 0, 0);
        #pragma unroll
        for (int ft = 0; ft < 2; ++ft) {
            int f0 = featBase + ft * 16 + q * 4;
            float b0 = bias[f0], b1 = bias[f0 + 1], b2 = bias[f0 + 2], b3 = bias[f0 + 3];
            #pragma unroll
            for (int nt = 0; nt < 2; ++nt) {
                int node = nodeBase + nt * 16 + li;
                if (node >= M) continue;
                float4 o;
                o.x = acc[ft][nt][0] + b0; o.y = acc[ft][nt][1] + b1;
                o.z = acc[ft][nt][2] + b2; o.w = acc[ft][nt][3] + b3;
                *(float4*)(out + (size_t)node * IN_DIM_ + f0) = o;
            }
        }
    }
}

// ----------------- fused attention: 3 relations + head-mean ------------------
// One wave per dst node (round-5 structure, proven ~85us; plateau — see r7
// post-mortem: ~5.4 TB/s through L3, near random-line service ceiling).

#define AGG_ISSUE8(R, sv, j0, cnt, proj) do {                                   \
    _Pragma("unroll")                                                           \
    for (int t_ = 0; t_ < 8; ++t_) {                                            \
        if (t_ < (cnt)) {                                                       \
            int idx_ = __shfl((sv), (j0) + t_, 64);                             \
            (R)[t_] = *(const uint2*)((proj) + (size_t)idx_ * 512 + lane * 4);  \
        }                                                                       \
    }                                                                           \
} while (0)

#define AGG_PROC8(R, cnt) do {                                                  \
    _Pragma("unroll")                                                           \
    for (int t_ = 0; t_ < 8; ++t_) {                                            \
        if (t_ < (cnt)) {                                                       \
            float s0_ = __uint_as_float((R)[t_].x << 16);                       \
            float s1_ = __uint_as_float((R)[t_].x & 0xffff0000u);               \
            float s2_ = __uint_as_float((R)[t_].y << 16);                       \
            float s3_ = __uint_as_float((R)[t_].y & 0xffff0000u);               \
            float p_ = s0_ * fd0_ + s1_ * fd1_ + s2_ * fd2_ + s3_ * fd3_;       \
            p_ = rowsum16(p_);                                                  \
            p_ = fminf(fmaxf(p_, -60.f), 60.f);                                 \
            float pe_ = __builtin_amdgcn_exp2f(p_);                             \
            den_ += pe_;                                                        \
            a0_ += pe_ * s0_; a1_ += pe_ * s1_;                                 \
            a2_ += pe_ * s2_; a3_ += pe_ * s3_;                                 \
        }                                                                       \
    }                                                                           \
} while (0)

#define AGG_REL(proj, fdr, sv, deg, cs, rv, cB) do {                            \
    if ((deg) > 0) {                                                            \
        float fd0_ = bf2f((fdr).x & 0xffff) * FS;                               \
        float fd1_ = __uint_as_float((fdr).x & 0xffff0000u) * FS;               \
        float fd2_ = bf2f((fdr).y & 0xffff) * FS;                               \
        float fd3_ = __uint_as_float((fdr).y & 0xffff0000u) * FS;               \
        float den_ = 0.f, a0_ = 0.f, a1_ = 0.f, a2_ = 0.f, a3_ = 0.f;           \
        AGG_PROC8(rv, cB);                                                      \
        int e_ = (cB);                                                          \
        int sv_ = (sv);                                                         \
        while (e_ < (deg)) {                                                    \
            if ((e_ & 63) == 0) {                                               \
                int o_ = e_ + lane;                                             \
                sv_ = (o_ < (deg)) ? (cs)[o_] : 0;                              \
            }                                                                   \
            int nt_ = (deg) - e_; if (nt_ > 8) nt_ = 8;                         \
            uint2 rt_[8];                                                       \
            AGG_ISSUE8(rt_, sv_, (e_ & 63), nt_, proj);                         \
            AGG_PROC8(rt_, nt_);                                                \
            e_ += nt_;                                                          \
        }                                                                       \
        float inv_ = 1.0f / fmaxf(den_, 1e-9f);                                 \
        t0 += a0_ * inv_; t1 += a1_ * inv_;                                     \
        t2 += a2_ * inv_; t3 += a3_ * inv_;                                     \
    }                                                                           \
} while (0)

__global__ __launch_bounds__(256) void agg_fused(const int* __restrict__ row_off,
                                                 const int* __restrict__ csr_src,
                                                 const unsigned short* __restrict__ p0,
                                                 const unsigned short* __restrict__ p1,
                                                 const unsigned short* __restrict__ p2,
                                                 unsigned short* __restrict__ hm) {
    int wave = (blockIdx.x * 256 + threadIdx.x) >> 6;
    int lane = threadIdx.x & 63;
    if (wave >= N_NODES) return;
    int dst = wave;
    const float FS = ATT_SCALE * LOG2E;

    const int* ro0 = row_off;
    const int* ro1 = row_off + (N_NODES + 1);
    const int* ro2 = row_off + 2 * (N_NODES + 1);
    int b0 = ro0[dst], e0 = ro0[dst + 1];
    int b1 = ro1[dst], e1 = ro1[dst + 1];
    int b2 = ro2[dst], e2 = ro2[dst + 1];
    uint2 fdr0 = *(const uint2*)(p0 + (size_t)dst * 512 + 256 + lane * 4);
    uint2 fdr1 = *(const uint2*)(p1 + (size_t)dst * 512 + 256 + lane * 4);
    uint2 fdr2 = *(const uint2*)(p2 + (size_t)dst * 512 + 256 + lane * 4);
    int deg0 = e0 - b0, deg1 = e1 - b1, deg2 = e2 - b2;

    const int* cs0 = csr_src + b0;
    const int* cs1 = csr_src + E_EDGES + b1;
    const int* cs2 = csr_src + 2 * E_EDGES + b2;
    int sv0 = (lane < deg0) ? cs0[lane] : 0;
    int sv1 = (lane < deg1) ? cs1[lane] : 0;
    int sv2 = (lane < deg2) ? cs2[lane] : 0;

    uint2 rv0[8], rv1[8], rv2[8];
    int c0 = deg0 < 8 ? deg0 : 8;
    int c1 = deg1 < 8 ? deg1 : 8;
    int c2 = deg2 < 8 ? deg2 : 8;
    AGG_ISSUE8(rv0, sv0, 0, c0, p0);
    AGG_ISSUE8(rv1, sv1, 0, c1, p1);
    AGG_ISSUE8(rv2, sv2, 0, c2, p2);

    float t0 = 0.f, t1 = 0.f, t2 = 0.f, t3 = 0.f;
    AGG_REL(p0, fdr0, sv0, deg0, cs0, rv0, c0);
    AGG_REL(p1, fdr1, sv1, deg1, cs1, rv1, c1);
    AGG_REL(p2, fdr2, sv2, deg2, cs2, rv2, c2);

    t0 += __shfl_xor(t0, 16, 64); t0 += __shfl_xor(t0, 32, 64);
    t1 += __shfl_xor(t1, 16, 64); t1 += __shfl_xor(t1, 32, 64);
    t2 += __shfl_xor(t2, 16, 64); t2 += __shfl_xor(t2, 32, 64);
    t3 += __shfl_xor(t3, 16, 64); t3 += __shfl_xor(t3, 32, 64);
    if (lane < 16) {
        unsigned lo = (unsigned)f2bf(t0 * 0.25f) | ((unsigned)f2bf(t1 * 0.25f) << 16);
        unsigned hi = (unsigned)f2bf(t2 * 0.25f) | ((unsigned)f2bf(t3 * 0.25f) << 16);
        uint2 pk; pk.x = lo; pk.y = hi;
        *(uint2*)(hm + (size_t)dst * 64 + lane * 4) = pk;
    }
}

// ----------------------------- launch ----------------------------------------

extern "C" void kernel_launch(void* const* d_in, const int* in_sizes, int n_in,
                              void* d_out, int out_size, void* d_ws, size_t ws_size,
                              hipStream_t stream) {
    const float* x     = (const float*)d_in[0];
    const int* srcs[3] = {(const int*)d_in[1], (const int*)d_in[3], (const int*)d_in[5]};
    const int* dsts[3] = {(const int*)d_in[2], (const int*)d_in[4], (const int*)d_in[6]};
    const float* Wsrc  = (const float*)d_in[7];
    const float* Wdst  = (const float*)d_in[8];
    const float* Wfc   = (const float*)d_in[9];
    const float* bfc   = (const float*)d_in[10];
    const float* gamma = (const float*)d_in[11];
    const float* beta  = (const float*)d_in[12];
    const float* Wdim  = (const float*)d_in[13];
    const float* bdim  = (const float*)d_in[14];
    float* out = (float*)d_out;

    char* ws = (char*)d_ws;
    size_t off = 0;
    auto alloc = [&](size_t bytes) -> void* {
        void* p = ws + off;
        off += (bytes + 255) & ~(size_t)255;
        return p;
    };
    // stats8 + bcur contiguous so one memset zeros both
    float* stats8 = (float*)alloc((size_t)2 * 8 * 128 * 4);     // [l][copy][128]
    int* bcur     = (int*)alloc((size_t)3 * NBUCK * BCSTR * 4); // 1 line per counter
    int* bstart   = (int*)alloc((size_t)3 * NBUCK * 4);
    int* row_off  = (int*)alloc((size_t)3 * (N_NODES + 1) * 4);
    int* csr_src  = (int*)alloc((size_t)3 * E_EDGES * 4);
    unsigned* ebuf = (unsigned*)alloc((size_t)3 * NBUCK * BCAP * 4);
    unsigned short* proj0 = (unsigned short*)alloc((size_t)N_NODES * 512 * 2);
    unsigned short* proj1 = (unsigned short*)alloc((size_t)N_NODES * 512 * 2);
    unsigned short* proj2 = (unsigned short*)alloc((size_t)N_NODES * 512 * 2);
    unsigned short* hm    = (unsigned short*)alloc((size_t)N_NODES * HID * 2);
    float* ybuf           = (float*)alloc((size_t)N_NODES * HID * 4);
    unsigned short* xb    = (unsigned short*)alloc((size_t)N_NODES * HID * 2);
    unsigned short* WtRel = (unsigned short*)alloc((size_t)PACK_REL * 2);
    unsigned short* WtFc  = (unsigned short*)alloc((size_t)PACK_FC * 2);
    unsigned short* WtDim = (unsigned short*)alloc((size_t)PACK_DIM * 2);

    // one memset covers stats8 (8 KB) + bcur (300 KB), contiguous
    hipMemsetAsync(stats8, 0, (size_t)2 * 8 * 128 * 4 + (size_t)3 * NBUCK * BCSTR * 4, stream);

    // U1: bucket-append ∪ weight-pack ∪ x->bf16 cast
    u1_kernel<<<HIST_B + PACK_B + CVT_B, 256, 0, stream>>>(
        srcs[0], dsts[0], srcs[1], dsts[1], srcs[2], dsts[2],
        bcur, ebuf, Wsrc, Wdst, Wfc, Wdim, WtRel, WtFc, WtDim, x, xb);

    // bucket prefix-sum (3 blocks)
    bscan_kernel<<<3, 1024, 0, stream>>>(bcur, bstart, row_off);

    // U2b: CSR build (writes row_off+csr_src) ∪ proj(layer 0 from xb)
    u2b_kernel<<<P2_B + PROJ_B, 256, 0, stream>>>(
        bstart, bcur, ebuf, csr_src, row_off, xb, WtRel, proj0, proj1, proj2);

    // layer 0
    agg_fused<<<(N_NODES + 3) / 4, 256, 0, stream>>>(row_off, csr_src,
                                                     proj0, proj1, proj2, hm);
    fc_bn_kernel<<<GX, 256, 0, stream>>>(hm, WtFc, bfc, ybuf, stats8, N_NODES);

    // layer 1: proj with fused BN-apply (l0 stats/params), then agg, then fc
    dim3 g(GX, 1, 3);
    proj_bn_kernel<<<g, 256, 0, stream>>>(ybuf, stats8, gamma, beta,
                                          WtRel + (size_t)3 * 512 * 64,
                                          proj0, proj1, proj2, N_NODES);
    agg_fused<<<(N_NODES + 3) / 4, 256, 0, stream>>>(row_off, csr_src,
                                                     proj0, proj1, proj2, hm);
    fc_bn_kernel<<<GX, 256, 0, stream>>>(hm, WtFc + (size_t)64 * 64, bfc + HID,
                                         ybuf, stats8 + 8 * 128, N_NODES);

    // final: 256-wide GEMM with fused BN-apply (l1 stats/params), by-folded
    gemm_fin_bn<<<GX, 256, 0, stream>>>(ybuf, stats8 + 8 * 128, gamma + HID, beta + HID,
                                        WtDim, bdim, out, N_NODES);
}